// Round 8
// baseline (340.955 us; speedup 1.0000x reference)
//
#include <hip/hip_runtime.h>
#include <hip/hip_fp16.h>

#define VD 256
#define HID 128
#define GD 256
#define NH 8
#define NGRAPH 4000   // num_graphs only available as device scalar; grid needs host value.
#define RT 64         // rows per k_stage1 tile
#define MAXROWS 512   // k_graph LDS score-staging cap (avg graph = 125 rows)

typedef _Float16 f16;
typedef f16 f16x4 __attribute__((ext_vector_type(4)));
typedef f16 f16x8 __attribute__((ext_vector_type(8)));
typedef float f32x4 __attribute__((ext_vector_type(4)));

__device__ __forceinline__ f16x8 load_a_frag(const float* p) {
  float4 p0 = *(const float4*)(p);
  float4 p1 = *(const float4*)(p + 4);
  f16x8 v;
  v[0] = (f16)p0.x; v[1] = (f16)p0.y; v[2] = (f16)p0.z; v[3] = (f16)p0.w;
  v[4] = (f16)p1.x; v[5] = (f16)p1.y; v[6] = (f16)p1.z; v[7] = (f16)p1.w;
  return v;
}

// Pack B operand [K][Nsrc] f32 -> MFMA B-fragment order f16.
// frag (kb,nb): lane l, elem i holds B[kb*32 + (l>>4)*8 + i][nb*16 + (l&15)]
__device__ __forceinline__ void pack_b_dev(const float* __restrict__ src,
                                           f16* __restrict__ dst,
                                           int K, int Nsrc, int Ndst, int t) {
  int NB = Ndst / 16, KB = K / 32;
  int total = KB * NB * 64;
  if (t >= total) return;
  int lane = t & 63;
  int frag = t >> 6;
  int nb = frag % NB, kb = frag / NB;
  int col = nb * 16 + (lane & 15);
  int krow = kb * 32 + (lane >> 4) * 8;
  f16x8 o;
  #pragma unroll
  for (int i = 0; i < 8; ++i) {
    float v = (col < Nsrc) ? src[(size_t)(krow + i) * Nsrc + col] : 0.0f;
    o[i] = (f16)v;
  }
  *(f16x8*)(dst + (size_t)t * 8) = o;
}

// One launch for all weight packing + segment bounds.
__global__ __launch_bounds__(256) void k_prep(
    const float* __restrict__ w1s, const float* __restrict__ w1t,
    const float* __restrict__ w2t, const float* __restrict__ w2s,
    const int* __restrict__ map,
    f16* __restrict__ W1sp, f16* __restrict__ W1tp,
    f16* __restrict__ W2tp, f16* __restrict__ W2sp,
    int* __restrict__ gs, int V, int G) {
  int b = blockIdx.x;
  int tid = threadIdx.x;
  if (b < 16) {
    pack_b_dev(w1s, W1sp, VD, HID, HID, b * 256 + tid);
  } else if (b < 32) {
    pack_b_dev(w1t, W1tp, VD, HID, HID, (b - 16) * 256 + tid);
  } else if (b < 48) {
    pack_b_dev(w2t, W2tp, HID, GD, GD, (b - 32) * 256 + tid);
  } else if (b == 48) {
    pack_b_dev(w2s, W2sp, HID, NH, 16, tid);
  } else {
    int g = (b - 49) * 256 + tid;
    if (g > G) return;
    int lo = 0, hi = V;
    while (lo < hi) {
      int mid = (lo + hi) >> 1;
      if (map[mid] < g) lo = mid + 1; else hi = mid;
    }
    gs[g] = lo;
  }
}

// Phase 1: one pass over E. Grid-stride over 64-row tiles (4 tiles/block):
// B-frags register-resident across tiles; next tile's E prefetched into
// registers while current tile runs MFMA.
// waves_per_eu pinned to (4,4): LDS caps at 2 blocks/CU anyway; a higher
// occupancy target makes the allocator choose 64 VGPR and spill Bs/Bt
// (R5: +350 MB scratch traffic, 2.5x dur).
__global__ __attribute__((amdgpu_flat_work_group_size(512, 512),
                          amdgpu_waves_per_eu(4, 4))) void k_stage1(
    const float* __restrict__ E, int V, int ntiles,
    const f16* __restrict__ W1sp, const f16* __restrict__ W2sp,
    const f16* __restrict__ W1tp,
    float* __restrict__ scores, f16* __restrict__ ht) {
  __shared__ __attribute__((aligned(16))) f16 lE[RT][VD + 8];
  __shared__ __attribute__((aligned(16))) f16 lH[RT][HID + 8];
  __shared__ __attribute__((aligned(16))) f16 lT[RT][HID + 8];
  const int tid = threadIdx.x;
  const int wave = tid >> 6;
  const int lane = tid & 63;
  const int hi = lane >> 4;
  const int lo = lane & 15;
  const int srow = tid >> 6;        // staging: 8 chunks/thread
  const int scol = (tid & 63) * 4;

  // B fragments: loaded once per block, register-resident for all tiles.
  f16x8 Bs[8], Bt[8];
  #pragma unroll
  for (int kb = 0; kb < 8; ++kb) {
    Bs[kb] = *(const f16x8*)(W1sp + ((size_t)(kb * 8 + wave) * 64 + lane) * 8);
    Bt[kb] = *(const f16x8*)(W1tp + ((size_t)(kb * 8 + wave) * 64 + lane) * 8);
  }

  int t = blockIdx.x;
  if (t >= ntiles) return;
  const int stride = gridDim.x;

  float4 pf[8];
  {
    const int r0 = t * RT;
    #pragma unroll
    for (int p = 0; p < 8; ++p) {
      int grow = r0 + p * 8 + srow;
      pf[p] = (grow < V) ? *(const float4*)(E + (size_t)grow * VD + scol)
                         : make_float4(0.f, 0.f, 0.f, 0.f);
    }
  }

  while (t < ntiles) {
    const int r0 = t * RT;
    // Write prefetched tile -> LDS (convert f32->f16 once).
    #pragma unroll
    for (int p = 0; p < 8; ++p) {
      f16x4 h;
      h[0] = (f16)pf[p].x; h[1] = (f16)pf[p].y;
      h[2] = (f16)pf[p].z; h[3] = (f16)pf[p].w;
      *(f16x4*)&lE[p * 8 + srow][scol] = h;
    }
    // Issue next tile's loads (consumed at next iteration's LDS write).
    const int tn = t + stride;
    if (tn < ntiles) {
      const int rn = tn * RT;
      #pragma unroll
      for (int p = 0; p < 8; ++p) {
        int grow = rn + p * 8 + srow;
        pf[p] = (grow < V) ? *(const float4*)(E + (size_t)grow * VD + scol)
                           : make_float4(0.f, 0.f, 0.f, 0.f);
      }
    }
    __syncthreads();   // lE ready; lH/lT free

    // Stage 1: h_s/h_t col-block `wave` for all 4 m-tiles.
    #pragma unroll
    for (int m = 0; m < 4; ++m) {
      f32x4 as = {0.f, 0.f, 0.f, 0.f};
      f32x4 at = {0.f, 0.f, 0.f, 0.f};
      #pragma unroll
      for (int kb = 0; kb < 8; ++kb) {
        f16x8 a = *(const f16x8*)&lE[m * 16 + lo][kb * 32 + hi * 8];
        as = __builtin_amdgcn_mfma_f32_16x16x32_f16(a, Bs[kb], as, 0, 0, 0);
        at = __builtin_amdgcn_mfma_f32_16x16x32_f16(a, Bt[kb], at, 0, 0, 0);
      }
      #pragma unroll
      for (int r = 0; r < 4; ++r) {
        lH[m * 16 + hi * 4 + r][wave * 16 + lo] = (f16)fmaxf(as[r], 0.f);
        if (ht != nullptr)
          lT[m * 16 + hi * 4 + r][wave * 16 + lo] = (f16)fmaxf(at[r], 0.f);
      }
    }
    __syncthreads();   // lH/lT ready; lE reads done

    if (wave < 4) {
      // Stage 2 (waves 0-3): scores = h_s @ W2s for m-block = wave.
      f16x8 a2[4];
      #pragma unroll
      for (int kb = 0; kb < 4; ++kb)
        a2[kb] = *(const f16x8*)&lH[wave * 16 + lo][kb * 32 + hi * 8];
      f32x4 acc = {0.f, 0.f, 0.f, 0.f};
      #pragma unroll
      for (int kb = 0; kb < 4; ++kb) {
        f16x8 b = *(const f16x8*)(W2sp + ((size_t)kb * 64 + lane) * 8);
        acc = __builtin_amdgcn_mfma_f32_16x16x32_f16(a2[kb], b, acc, 0, 0, 0);
      }
      if (lo < NH) {
        #pragma unroll
        for (int r = 0; r < 4; ++r) {
          int row = r0 + wave * 16 + hi * 4 + r;
          if (row < V) scores[(size_t)row * NH + lo] = acc[r];
        }
      }
    } else if (ht != nullptr) {
      // Waves 4-7: ht -> global (coalesced f16x8), overlapping stage-2 MFMA.
      const int base = tid - 256;
      #pragma unroll
      for (int p = 0; p < 4; ++p) {
        int c = p * 256 + base;
        int row = c >> 4;
        int col = (c & 15) * 8;
        int grow = r0 + row;
        if (grow < V)
          *(f16x8*)(ht + (size_t)grow * HID + col) = *(const f16x8*)&lT[row][col];
      }
    }
    t = tn;
  }
}

// Phase 2 fused with softmax stats: per-graph WG, 512 threads, 8 waves.
// Wave w owns head w (cols w*32..w*32+31): B-frags (32 VGPR) in registers.
// Graph's scores staged to LDS once, stats from LDS, LDS overwritten with
// final weights. Main loop: 32 rows/iter, all 8 ht loads issued before MFMA
// (2x MLP + half the dependent-chain length vs 16 rows/iter).
__global__ __attribute__((amdgpu_flat_work_group_size(512, 512),
                          amdgpu_waves_per_eu(4, 4))) void k_graph(
    const f16* __restrict__ ht, const float* __restrict__ scores,
    const f16* __restrict__ W2tp, const int* __restrict__ gs,
    float* __restrict__ out, int V) {
  __shared__ float red[8][NH];
  __shared__ float lW[MAXROWS * NH];   // 16 KB
  const int g = blockIdx.x;
  const int tid = threadIdx.x;
  const int wave = tid >> 6;
  const int lane = tid & 63;
  const int hi = lane >> 4;
  const int lo = lane & 15;
  const int s = gs[g], e = gs[g + 1];
  const int n = e - s;

  if (n <= 0) {
    if (tid < GD) out[(size_t)g * GD + tid] = 0.f;
    return;
  }

  // B frags for head `wave`: n-blocks 2*wave, 2*wave+1.
  f16x8 b[2][4];
  #pragma unroll
  for (int nb = 0; nb < 2; ++nb)
    #pragma unroll
    for (int kb = 0; kb < 4; ++kb)
      b[nb][kb] = *(const f16x8*)(
          W2tp + ((size_t)(kb * 16 + wave * 2 + nb) * 64 + lane) * 8);

  float mh, rih;
  const bool use_lds = (n <= MAXROWS);

  if (use_lds) {
    // Stage scores -> LDS (coalesced float4).
    for (int c = tid; c < n * 2; c += 512)
      *(float4*)&lW[c * 4] = *(const float4*)(scores + (size_t)s * NH + c * 4);
    __syncthreads();

    float mx[NH];
    #pragma unroll
    for (int h = 0; h < NH; ++h) mx[h] = -1e30f;
    for (int i = tid; i < n; i += 512) {
      #pragma unroll
      for (int h = 0; h < NH; ++h) mx[h] = fmaxf(mx[h], lW[i * NH + h]);
    }
    #pragma unroll
    for (int off = 32; off >= 1; off >>= 1)
      #pragma unroll
      for (int h = 0; h < NH; ++h) mx[h] = fmaxf(mx[h], __shfl_xor(mx[h], off));
    if (lane == 0) {
      #pragma unroll
      for (int h = 0; h < NH; ++h) red[wave][h] = mx[h];
    }
    __syncthreads();
    #pragma unroll
    for (int h = 0; h < NH; ++h) {
      float m01 = fmaxf(red[0][h], red[1][h]);
      float m23 = fmaxf(red[2][h], red[3][h]);
      float m45 = fmaxf(red[4][h], red[5][h]);
      float m67 = fmaxf(red[6][h], red[7][h]);
      mx[h] = fmaxf(fmaxf(m01, m23), fmaxf(m45, m67));
    }
    __syncthreads();

    float sm[NH];
    #pragma unroll
    for (int h = 0; h < NH; ++h) sm[h] = 0.f;
    for (int i = tid; i < n; i += 512) {
      #pragma unroll
      for (int h = 0; h < NH; ++h) sm[h] += __expf(lW[i * NH + h] - mx[h]);
    }
    #pragma unroll
    for (int off = 32; off >= 1; off >>= 1)
      #pragma unroll
      for (int h = 0; h < NH; ++h) sm[h] += __shfl_xor(sm[h], off);
    if (lane == 0) {
      #pragma unroll
      for (int h = 0; h < NH; ++h) red[wave][h] = sm[h];
    }
    __syncthreads();

    float rinv[NH];
    #pragma unroll
    for (int h = 0; h < NH; ++h)
      rinv[h] = 1.f / (red[0][h] + red[1][h] + red[2][h] + red[3][h] +
                       red[4][h] + red[5][h] + red[6][h] + red[7][h]);

    // Overwrite LDS scores with final weights.
    for (int i = tid; i < n; i += 512) {
      #pragma unroll
      for (int h = 0; h < NH; ++h)
        lW[i * NH + h] = __expf(lW[i * NH + h] - mx[h]) * rinv[h];
    }
    __syncthreads();
    mh = mx[wave]; rih = rinv[wave];
  } else {
    // Fallback: stats straight from global (rare: n > MAXROWS).
    float mx[NH];
    #pragma unroll
    for (int h = 0; h < NH; ++h) mx[h] = -1e30f;
    for (int i = s + tid; i < e; i += 512) {
      float4 s0 = *(const float4*)(scores + (size_t)i * NH);
      float4 s1 = *(const float4*)(scores + (size_t)i * NH + 4);
      mx[0] = fmaxf(mx[0], s0.x); mx[1] = fmaxf(mx[1], s0.y);
      mx[2] = fmaxf(mx[2], s0.z); mx[3] = fmaxf(mx[3], s0.w);
      mx[4] = fmaxf(mx[4], s1.x); mx[5] = fmaxf(mx[5], s1.y);
      mx[6] = fmaxf(mx[6], s1.z); mx[7] = fmaxf(mx[7], s1.w);
    }
    #pragma unroll
    for (int off = 32; off >= 1; off >>= 1)
      #pragma unroll
      for (int h = 0; h < NH; ++h) mx[h] = fmaxf(mx[h], __shfl_xor(mx[h], off));
    if (lane == 0) {
      #pragma unroll
      for (int h = 0; h < NH; ++h) red[wave][h] = mx[h];
    }
    __syncthreads();
    #pragma unroll
    for (int h = 0; h < NH; ++h) {
      float m01 = fmaxf(red[0][h], red[1][h]);
      float m23 = fmaxf(red[2][h], red[3][h]);
      float m45 = fmaxf(red[4][h], red[5][h]);
      float m67 = fmaxf(red[6][h], red[7][h]);
      mx[h] = fmaxf(fmaxf(m01, m23), fmaxf(m45, m67));
    }
    __syncthreads();

    float sm[NH];
    #pragma unroll
    for (int h = 0; h < NH; ++h) sm[h] = 0.f;
    for (int i = s + tid; i < e; i += 512) {
      float4 s0 = *(const float4*)(scores + (size_t)i * NH);
      float4 s1 = *(const float4*)(scores + (size_t)i * NH + 4);
      sm[0] += __expf(s0.x - mx[0]); sm[1] += __expf(s0.y - mx[1]);
      sm[2] += __expf(s0.z - mx[2]); sm[3] += __expf(s0.w - mx[3]);
      sm[4] += __expf(s1.x - mx[4]); sm[5] += __expf(s1.y - mx[5]);
      sm[6] += __expf(s1.z - mx[6]); sm[7] += __expf(s1.w - mx[7]);
    }
    #pragma unroll
    for (int off = 32; off >= 1; off >>= 1)
      #pragma unroll
      for (int h = 0; h < NH; ++h) sm[h] += __shfl_xor(sm[h], off);
    if (lane == 0) {
      #pragma unroll
      for (int h = 0; h < NH; ++h) red[wave][h] = sm[h];
    }
    __syncthreads();
    mh = mx[wave];
    rih = 1.f / (red[0][wave] + red[1][wave] + red[2][wave] + red[3][wave] +
                 red[4][wave] + red[5][wave] + red[6][wave] + red[7][wave]);
  }

  float vs0 = 0.f, vs1 = 0.f;

  for (int cb = s; cb < e; cb += 32) {
    // All 8 A-frag loads issued before any MFMA (chunks A: rows cb..cb+15,
    // B: rows cb+16..cb+31).
    f16x8 aA[4], aB[4];
    int rA = cb + lo;       rA = rA < V ? rA : V - 1;
    int rB = cb + 16 + lo;  rB = rB < V ? rB : V - 1;
    #pragma unroll
    for (int kb = 0; kb < 4; ++kb)
      aA[kb] = *(const f16x8*)(ht + (size_t)rA * HID + kb * 32 + hi * 8);
    #pragma unroll
    for (int kb = 0; kb < 4; ++kb)
      aB[kb] = *(const f16x8*)(ht + (size_t)rB * HID + kb * 32 + hi * 8);

    float wA[4], wB[4];
    if (use_lds) {
      #pragma unroll
      for (int r = 0; r < 4; ++r) {
        int rowA = cb + hi * 4 + r;
        int rowB = rowA + 16;
        wA[r] = (rowA < e) ? lW[(rowA - s) * NH + wave] : 0.f;
        wB[r] = (rowB < e) ? lW[(rowB - s) * NH + wave] : 0.f;
      }
    } else {
      #pragma unroll
      for (int r = 0; r < 4; ++r) {
        int rowA = cb + hi * 4 + r;
        int rowB = rowA + 16;
        wA[r] = (rowA < e) ? __expf(scores[(size_t)rowA * NH + wave] - mh) * rih
                           : 0.f;
        wB[r] = (rowB < e) ? __expf(scores[(size_t)rowB * NH + wave] - mh) * rih
                           : 0.f;
      }
    }

    #pragma unroll
    for (int nb = 0; nb < 2; ++nb) {
      f32x4 accA = {0.f, 0.f, 0.f, 0.f};
      #pragma unroll
      for (int kb = 0; kb < 4; ++kb)
        accA = __builtin_amdgcn_mfma_f32_16x16x32_f16(aA[kb], b[nb][kb], accA, 0, 0, 0);
      f32x4 accB = {0.f, 0.f, 0.f, 0.f};
      #pragma unroll
      for (int kb = 0; kb < 4; ++kb)
        accB = __builtin_amdgcn_mfma_f32_16x16x32_f16(aB[kb], b[nb][kb], accB, 0, 0, 0);
      float v = 0.f;
      #pragma unroll
      for (int r = 0; r < 4; ++r) v += fmaxf(accA[r], 0.f) * wA[r];
      #pragma unroll
      for (int r = 0; r < 4; ++r) v += fmaxf(accB[r], 0.f) * wB[r];
      if (nb == 0) vs0 += v; else vs1 += v;
    }
  }

  #pragma unroll
  for (int nb = 0; nb < 2; ++nb) {
    float v = (nb == 0) ? vs0 : vs1;
    v += __shfl_xor(v, 16);
    v += __shfl_xor(v, 32);
    if (lane < 16)
      out[(size_t)g * GD + wave * 32 + nb * 16 + lo] = v;
  }
}

// ---- fallback path (ws too small for ht): old stats + recompute kernels ----
__global__ __launch_bounds__(64) void k_stats(
    float* __restrict__ scores, const int* __restrict__ gs) {
  int g = blockIdx.x;
  int lane = threadIdx.x;
  int s = gs[g], e = gs[g + 1];
  if (e <= s) return;
  float mx[NH];
  #pragma unroll
  for (int h = 0; h < NH; ++h) mx[h] = -1e30f;
  for (int i = s + lane; i < e; i += 64) {
    float4 s0 = *(const float4*)(scores + (size_t)i * NH);
    float4 s1 = *(const float4*)(scores + (size_t)i * NH + 4);
    mx[0] = fmaxf(mx[0], s0.x); mx[1] = fmaxf(mx[1], s0.y);
    mx[2] = fmaxf(mx[2], s0.z); mx[3] = fmaxf(mx[3], s0.w);
    mx[4] = fmaxf(mx[4], s1.x); mx[5] = fmaxf(mx[5], s1.y);
    mx[6] = fmaxf(mx[6], s1.z); mx[7] = fmaxf(mx[7], s1.w);
  }
  #pragma unroll
  for (int off = 32; off >= 1; off >>= 1)
    #pragma unroll
    for (int h = 0; h < NH; ++h) mx[h] = fmaxf(mx[h], __shfl_xor(mx[h], off));
  float sm[NH];
  #pragma unroll
  for (int h = 0; h < NH; ++h) sm[h] = 0.f;
  for (int i = s + lane; i < e; i += 64) {
    float4 s0 = *(const float4*)(scores + (size_t)i * NH);
    float4 s1 = *(const float4*)(scores + (size_t)i * NH + 4);
    sm[0] += __expf(s0.x - mx[0]); sm[1] += __expf(s0.y - mx[1]);
    sm[2] += __expf(s0.z - mx[2]); sm[3] += __expf(s0.w - mx[3]);
    sm[4] += __expf(s1.x - mx[4]); sm[5] += __expf(s1.y - mx[5]);
    sm[6] += __expf(s1.z - mx[6]); sm[7] += __expf(s1.w - mx[7]);
  }
  #pragma unroll
  for (int off = 32; off >= 1; off >>= 1)
    #pragma unroll
    for (int h = 0; h < NH; ++h) sm[h] += __shfl_xor(sm[h], off);
  float rinv[NH];
  #pragma unroll
  for (int h = 0; h < NH; ++h) rinv[h] = 1.f / sm[h];
  for (int i = s + lane; i < e; i += 64) {
    float4 s0 = *(const float4*)(scores + (size_t)i * NH);
    float4 s1 = *(const float4*)(scores + (size_t)i * NH + 4);
    s0.x = __expf(s0.x - mx[0]) * rinv[0]; s0.y = __expf(s0.y - mx[1]) * rinv[1];
    s0.z = __expf(s0.z - mx[2]) * rinv[2]; s0.w = __expf(s0.w - mx[3]) * rinv[3];
    s1.x = __expf(s1.x - mx[4]) * rinv[4]; s1.y = __expf(s1.y - mx[5]) * rinv[5];
    s1.z = __expf(s1.z - mx[6]) * rinv[6]; s1.w = __expf(s1.w - mx[7]) * rinv[7];
    *(float4*)(scores + (size_t)i * NH) = s0;
    *(float4*)(scores + (size_t)i * NH + 4) = s1;
  }
}

__global__ __launch_bounds__(256, 2) void k_transform2(
    const float* __restrict__ E, int V,
    const f16* __restrict__ W1tp, const f16* __restrict__ W2tp,
    const float* __restrict__ w, const int* __restrict__ gs,
    float* __restrict__ out) {
  __shared__ f16 hl[16][HID + 8];
  const int g = blockIdx.x;
  const int wave = threadIdx.x >> 6;
  const int lane = threadIdx.x & 63;
  const int hi = lane >> 4;
  const int lo = lane & 15;
  const int s = gs[g], e = gs[g + 1];

  f16x8 b[4][4];
  #pragma unroll
  for (int j = 0; j < 4; ++j)
    #pragma unroll
    for (int kb = 0; kb < 4; ++kb)
      b[j][kb] = *(const f16x8*)(
          W2tp + ((size_t)(kb * 16 + wave * 4 + j) * 64 + lane) * 8);

  float vsum[4] = {0.f, 0.f, 0.f, 0.f};

  for (int cb = s; cb < e; cb += 16) {
    int arow = cb + lo;
    int ar = arow < V ? arow : V - 1;
    f16x8 a[8];
    const float* ep = E + (size_t)ar * VD + hi * 8;
    #pragma unroll
    for (int kb = 0; kb < 8; ++kb) a[kb] = load_a_frag(ep + kb * 32);

    __syncthreads();
    #pragma unroll
    for (int nn = 0; nn < 2; ++nn) {
      int n = wave * 2 + nn;
      f32x4 acc = {0.f, 0.f, 0.f, 0.f};
      #pragma unroll
      for (int kb = 0; kb < 8; ++kb) {
        f16x8 bb = *(const f16x8*)(W1tp + ((size_t)(kb * 8 + n) * 64 + lane) * 8);
        acc = __builtin_amdgcn_mfma_f32_16x16x32_f16(a[kb], bb, acc, 0, 0, 0);
      }
      #pragma unroll
      for (int r = 0; r < 4; ++r)
        hl[hi * 4 + r][n * 16 + lo] = (f16)fmaxf(acc[r], 0.f);
    }
    __syncthreads();

    int wr = cb + hi * 4;
    float wv[2][4];
    #pragma unroll
    for (int hh = 0; hh < 2; ++hh) {
      int head = wave * 2 + hh;
      #pragma unroll
      for (int r = 0; r < 4; ++r) {
        int row = wr + r;
        wv[hh][r] = (row < e) ? w[(size_t)row * NH + head] : 0.f;
      }
    }
    f16x8 a2[4];
    #pragma unroll
    for (int kb = 0; kb < 4; ++kb)
      a2[kb] = *(const f16x8*)&hl[lo][kb * 32 + hi * 8];
    #pragma unroll
    for (int j = 0; j < 4; ++j) {
      f32x4 acc = {0.f, 0.f, 0.f, 0.f};
      #pragma unroll
      for (int kb = 0; kb < 4; ++kb)
        acc = __builtin_amdgcn_mfma_f32_16x16x32_f16(a2[kb], b[j][kb], acc, 0, 0, 0);
      const float* wvp = wv[j >> 1];
      float v = 0.f;
      #pragma unroll
      for (int r = 0; r < 4; ++r) v += fmaxf(acc[r], 0.f) * wvp[r];
      vsum[j] += v;
    }
  }

  #pragma unroll
  for (int j = 0; j < 4; ++j) {
    float v = vsum[j];
    v += __shfl_xor(v, 16);
    v += __shfl_xor(v, 32);
    if (lane < 16) out[(size_t)g * GD + (wave * 4 + j) * 16 + lo] = v;
  }
}

extern "C" void kernel_launch(void* const* d_in, const int* in_sizes, int n_in,
                              void* d_out, int out_size, void* d_ws, size_t ws_size,
                              hipStream_t stream) {
  const float* E   = (const float*)d_in[0];
  const int*   map = (const int*)d_in[1];
  const float* w1s = (const float*)d_in[3];
  const float* w2s = (const float*)d_in[4];
  const float* w1t = (const float*)d_in[5];
  const float* w2t = (const float*)d_in[6];
  const int V = in_sizes[0] / VD;
  const int G = NGRAPH;

  char* ws = (char*)d_ws;
  size_t off = 0;
  float* scores = (float*)(ws + off); off += (size_t)V * NH * 4;
  int* gs = (int*)(ws + off); off += (size_t)(G + 1) * 4;
  off = (off + 255) & ~(size_t)255;
  f16* W1sp = (f16*)(ws + off); off += (size_t)VD * HID * 2;
  f16* W1tp = (f16*)(ws + off); off += (size_t)VD * HID * 2;
  f16* W2tp = (f16*)(ws + off); off += (size_t)HID * GD * 2;
  f16* W2sp = (f16*)(ws + off); off += (size_t)HID * 16 * 2;
  off = (off + 255) & ~(size_t)255;
  f16* ht = (f16*)(ws + off);
  const size_t need_fused = off + (size_t)V * HID * 2;
  const bool fused = ws_size >= need_fused;

  k_prep<<<65, 256, 0, stream>>>(w1s, w1t, w2t, w2s, map,
                                 W1sp, W1tp, W2tp, W2sp, gs, V, G);

  const int ntiles = (V + RT - 1) / RT;
  const int grid1 = (ntiles + 3) / 4;
  k_stage1<<<grid1, 512, 0, stream>>>(
      E, V, ntiles, W1sp, W2sp, W1tp, scores, fused ? ht : nullptr);

  if (fused) {
    k_graph<<<G, 512, 0, stream>>>(ht, scores, W2tp, gs, (float*)d_out, V);
  } else {
    k_stats<<<G, 64, 0, stream>>>(scores, gs);
    k_transform2<<<G, 256, 0, stream>>>(E, V, W1tp, W2tp, scores, gs,
                                        (float*)d_out);
  }
}

// Round 9
// 322.765 us; speedup vs baseline: 1.0564x; 1.0564x over previous
//
#include <hip/hip_runtime.h>
#include <hip/hip_fp16.h>

#define VD 256
#define HID 128
#define GD 256
#define NH 8
#define NGRAPH 4000   // num_graphs only available as device scalar; grid needs host value.
#define RT 64         // rows per k_stage1 tile
#define MAXROWS 512   // k_graph LDS score-staging cap (avg graph = 125 rows)

typedef _Float16 f16;
typedef f16 f16x4 __attribute__((ext_vector_type(4)));
typedef f16 f16x8 __attribute__((ext_vector_type(8)));
typedef float f32x4 __attribute__((ext_vector_type(4)));

__device__ __forceinline__ f16x8 load_a_frag(const float* p) {
  float4 p0 = *(const float4*)(p);
  float4 p1 = *(const float4*)(p + 4);
  f16x8 v;
  v[0] = (f16)p0.x; v[1] = (f16)p0.y; v[2] = (f16)p0.z; v[3] = (f16)p0.w;
  v[4] = (f16)p1.x; v[5] = (f16)p1.y; v[6] = (f16)p1.z; v[7] = (f16)p1.w;
  return v;
}

// Pack B operand [K][Nsrc] f32 -> MFMA B-fragment order f16.
// frag (kb,nb): lane l, elem i holds B[kb*32 + (l>>4)*8 + i][nb*16 + (l&15)]
__device__ __forceinline__ void pack_b_dev(const float* __restrict__ src,
                                           f16* __restrict__ dst,
                                           int K, int Nsrc, int Ndst, int t) {
  int NB = Ndst / 16, KB = K / 32;
  int total = KB * NB * 64;
  if (t >= total) return;
  int lane = t & 63;
  int frag = t >> 6;
  int nb = frag % NB, kb = frag / NB;
  int col = nb * 16 + (lane & 15);
  int krow = kb * 32 + (lane >> 4) * 8;
  f16x8 o;
  #pragma unroll
  for (int i = 0; i < 8; ++i) {
    float v = (col < Nsrc) ? src[(size_t)(krow + i) * Nsrc + col] : 0.0f;
    o[i] = (f16)v;
  }
  *(f16x8*)(dst + (size_t)t * 8) = o;
}

// One launch for all weight packing + segment bounds.
__global__ __launch_bounds__(256) void k_prep(
    const float* __restrict__ w1s, const float* __restrict__ w1t,
    const float* __restrict__ w2t, const float* __restrict__ w2s,
    const int* __restrict__ map,
    f16* __restrict__ W1sp, f16* __restrict__ W1tp,
    f16* __restrict__ W2tp, f16* __restrict__ W2sp,
    int* __restrict__ gs, int V, int G) {
  int b = blockIdx.x;
  int tid = threadIdx.x;
  if (b < 16) {
    pack_b_dev(w1s, W1sp, VD, HID, HID, b * 256 + tid);
  } else if (b < 32) {
    pack_b_dev(w1t, W1tp, VD, HID, HID, (b - 16) * 256 + tid);
  } else if (b < 48) {
    pack_b_dev(w2t, W2tp, HID, GD, GD, (b - 32) * 256 + tid);
  } else if (b == 48) {
    pack_b_dev(w2s, W2sp, HID, NH, 16, tid);
  } else {
    int g = (b - 49) * 256 + tid;
    if (g > G) return;
    int lo = 0, hi = V;
    while (lo < hi) {
      int mid = (lo + hi) >> 1;
      if (map[mid] < g) lo = mid + 1; else hi = mid;
    }
    gs[g] = lo;
  }
}

// Phase 1: one pass over E. Grid-stride over 64-row tiles (4 tiles/block):
// B-frags register-resident across tiles; next tile's E prefetched into
// registers while current tile runs MFMA.
// waves_per_eu pinned to (4,4): LDS caps at 2 blocks/CU anyway; a higher
// occupancy target makes the allocator choose 64 VGPR and spill Bs/Bt
// (R5: +350 MB scratch traffic, 2.5x dur).
__global__ __attribute__((amdgpu_flat_work_group_size(512, 512),
                          amdgpu_waves_per_eu(4, 4))) void k_stage1(
    const float* __restrict__ E, int V, int ntiles,
    const f16* __restrict__ W1sp, const f16* __restrict__ W2sp,
    const f16* __restrict__ W1tp,
    float* __restrict__ scores, f16* __restrict__ ht) {
  __shared__ __attribute__((aligned(16))) f16 lE[RT][VD + 8];
  __shared__ __attribute__((aligned(16))) f16 lH[RT][HID + 8];
  __shared__ __attribute__((aligned(16))) f16 lT[RT][HID + 8];
  const int tid = threadIdx.x;
  const int wave = tid >> 6;
  const int lane = tid & 63;
  const int hi = lane >> 4;
  const int lo = lane & 15;
  const int srow = tid >> 6;        // staging: 8 chunks/thread
  const int scol = (tid & 63) * 4;

  // B fragments: loaded once per block, register-resident for all tiles.
  f16x8 Bs[8], Bt[8];
  #pragma unroll
  for (int kb = 0; kb < 8; ++kb) {
    Bs[kb] = *(const f16x8*)(W1sp + ((size_t)(kb * 8 + wave) * 64 + lane) * 8);
    Bt[kb] = *(const f16x8*)(W1tp + ((size_t)(kb * 8 + wave) * 64 + lane) * 8);
  }

  int t = blockIdx.x;
  if (t >= ntiles) return;
  const int stride = gridDim.x;

  float4 pf[8];
  {
    const int r0 = t * RT;
    #pragma unroll
    for (int p = 0; p < 8; ++p) {
      int grow = r0 + p * 8 + srow;
      pf[p] = (grow < V) ? *(const float4*)(E + (size_t)grow * VD + scol)
                         : make_float4(0.f, 0.f, 0.f, 0.f);
    }
  }

  while (t < ntiles) {
    const int r0 = t * RT;
    // Write prefetched tile -> LDS (convert f32->f16 once).
    #pragma unroll
    for (int p = 0; p < 8; ++p) {
      f16x4 h;
      h[0] = (f16)pf[p].x; h[1] = (f16)pf[p].y;
      h[2] = (f16)pf[p].z; h[3] = (f16)pf[p].w;
      *(f16x4*)&lE[p * 8 + srow][scol] = h;
    }
    // Issue next tile's loads (consumed at next iteration's LDS write).
    const int tn = t + stride;
    if (tn < ntiles) {
      const int rn = tn * RT;
      #pragma unroll
      for (int p = 0; p < 8; ++p) {
        int grow = rn + p * 8 + srow;
        pf[p] = (grow < V) ? *(const float4*)(E + (size_t)grow * VD + scol)
                           : make_float4(0.f, 0.f, 0.f, 0.f);
      }
    }
    __syncthreads();   // lE ready; lH/lT free

    // Stage 1: h_s/h_t col-block `wave` for all 4 m-tiles.
    #pragma unroll
    for (int m = 0; m < 4; ++m) {
      f32x4 as = {0.f, 0.f, 0.f, 0.f};
      f32x4 at = {0.f, 0.f, 0.f, 0.f};
      #pragma unroll
      for (int kb = 0; kb < 8; ++kb) {
        f16x8 a = *(const f16x8*)&lE[m * 16 + lo][kb * 32 + hi * 8];
        as = __builtin_amdgcn_mfma_f32_16x16x32_f16(a, Bs[kb], as, 0, 0, 0);
        at = __builtin_amdgcn_mfma_f32_16x16x32_f16(a, Bt[kb], at, 0, 0, 0);
      }
      #pragma unroll
      for (int r = 0; r < 4; ++r) {
        lH[m * 16 + hi * 4 + r][wave * 16 + lo] = (f16)fmaxf(as[r], 0.f);
        if (ht != nullptr)
          lT[m * 16 + hi * 4 + r][wave * 16 + lo] = (f16)fmaxf(at[r], 0.f);
      }
    }
    __syncthreads();   // lH/lT ready; lE reads done

    // ht -> global FIRST (fire-and-forget stores overlap the scores MFMA).
    if (ht != nullptr) {
      #pragma unroll
      for (int p = 0; p < 2; ++p) {
        int c = p * 512 + tid;
        int row = c >> 4;
        int col = (c & 15) * 8;
        int grow = r0 + row;
        if (grow < V)
          *(f16x8*)(ht + (size_t)grow * HID + col) = *(const f16x8*)&lT[row][col];
      }
    }

    // Stage 2 (waves 0-3): scores = h_s @ W2s for m-block = wave.
    if (wave < 4) {
      f16x8 a2[4];
      #pragma unroll
      for (int kb = 0; kb < 4; ++kb)
        a2[kb] = *(const f16x8*)&lH[wave * 16 + lo][kb * 32 + hi * 8];
      f32x4 acc = {0.f, 0.f, 0.f, 0.f};
      #pragma unroll
      for (int kb = 0; kb < 4; ++kb) {
        f16x8 b = *(const f16x8*)(W2sp + ((size_t)kb * 64 + lane) * 8);
        acc = __builtin_amdgcn_mfma_f32_16x16x32_f16(a2[kb], b, acc, 0, 0, 0);
      }
      if (lo < NH) {
        #pragma unroll
        for (int r = 0; r < 4; ++r) {
          int row = r0 + wave * 16 + hi * 4 + r;
          if (row < V) scores[(size_t)row * NH + lo] = acc[r];
        }
      }
    }
    t = tn;
  }
}

// Phase 2 fused with softmax stats: per-graph WG (4 waves). Graph's scores
// staged to LDS once (<=MAXROWS rows), stats computed from LDS, then LDS is
// overwritten in place with final softmax weights; main loop reads weights
// from LDS. Wave w owns cols [w*64, w*64+64); W2t B-frags in registers.
// Main loop uses T14 issue-early: next chunk's ht A-frags loaded before the
// current chunk's MFMA, halving the exposed HBM latency per iteration.
__global__ __attribute__((amdgpu_flat_work_group_size(256, 256),
                          amdgpu_waves_per_eu(4, 4))) void k_graph(
    const f16* __restrict__ ht, const float* __restrict__ scores,
    const f16* __restrict__ W2tp, const int* __restrict__ gs,
    float* __restrict__ out, int V) {
  __shared__ float red[4][NH];
  __shared__ float lW[MAXROWS * NH];   // 16 KB
  const int g = blockIdx.x;
  const int tid = threadIdx.x;
  const int wave = tid >> 6;
  const int lane = tid & 63;
  const int hi = lane >> 4;
  const int lo = lane & 15;
  const int s = gs[g], e = gs[g + 1];
  const int n = e - s;

  if (n <= 0) {
    out[(size_t)g * GD + tid] = 0.f;
    return;
  }

  f16x8 b[4][4];
  #pragma unroll
  for (int j = 0; j < 4; ++j)
    #pragma unroll
    for (int kb = 0; kb < 4; ++kb)
      b[j][kb] = *(const f16x8*)(
          W2tp + ((size_t)(kb * 16 + wave * 4 + j) * 64 + lane) * 8);

  const int h0 = wave * 2, h1 = wave * 2 + 1;
  float m0, m1, ri0, ri1;
  const bool use_lds = (n <= MAXROWS);

  if (use_lds) {
    // Stage scores -> LDS (coalesced float4; n*2 chunks).
    for (int c = tid; c < n * 2; c += 256)
      *(float4*)&lW[c * 4] = *(const float4*)(scores + (size_t)s * NH + c * 4);
    __syncthreads();

    // Per-head max from LDS.
    float mx[NH];
    #pragma unroll
    for (int h = 0; h < NH; ++h) mx[h] = -1e30f;
    for (int i = tid; i < n; i += 256) {
      #pragma unroll
      for (int h = 0; h < NH; ++h) mx[h] = fmaxf(mx[h], lW[i * NH + h]);
    }
    #pragma unroll
    for (int off = 32; off >= 1; off >>= 1)
      #pragma unroll
      for (int h = 0; h < NH; ++h) mx[h] = fmaxf(mx[h], __shfl_xor(mx[h], off));
    if (lane == 0) {
      #pragma unroll
      for (int h = 0; h < NH; ++h) red[wave][h] = mx[h];
    }
    __syncthreads();
    #pragma unroll
    for (int h = 0; h < NH; ++h)
      mx[h] = fmaxf(fmaxf(red[0][h], red[1][h]), fmaxf(red[2][h], red[3][h]));
    __syncthreads();

    // Per-head sum of exp from LDS.
    float sm[NH];
    #pragma unroll
    for (int h = 0; h < NH; ++h) sm[h] = 0.f;
    for (int i = tid; i < n; i += 256) {
      #pragma unroll
      for (int h = 0; h < NH; ++h) sm[h] += __expf(lW[i * NH + h] - mx[h]);
    }
    #pragma unroll
    for (int off = 32; off >= 1; off >>= 1)
      #pragma unroll
      for (int h = 0; h < NH; ++h) sm[h] += __shfl_xor(sm[h], off);
    if (lane == 0) {
      #pragma unroll
      for (int h = 0; h < NH; ++h) red[wave][h] = sm[h];
    }
    __syncthreads();

    float rinv[NH];
    #pragma unroll
    for (int h = 0; h < NH; ++h)
      rinv[h] = 1.f / (red[0][h] + red[1][h] + red[2][h] + red[3][h]);

    // Overwrite LDS scores with final weights.
    for (int i = tid; i < n; i += 256) {
      #pragma unroll
      for (int h = 0; h < NH; ++h)
        lW[i * NH + h] = __expf(lW[i * NH + h] - mx[h]) * rinv[h];
    }
    __syncthreads();
    m0 = mx[h0]; m1 = mx[h1]; ri0 = rinv[h0]; ri1 = rinv[h1];
  } else {
    // Fallback: stats straight from global (rare: n > MAXROWS).
    float mx[NH];
    #pragma unroll
    for (int h = 0; h < NH; ++h) mx[h] = -1e30f;
    for (int i = s + tid; i < e; i += 256) {
      float4 s0 = *(const float4*)(scores + (size_t)i * NH);
      float4 s1 = *(const float4*)(scores + (size_t)i * NH + 4);
      mx[0] = fmaxf(mx[0], s0.x); mx[1] = fmaxf(mx[1], s0.y);
      mx[2] = fmaxf(mx[2], s0.z); mx[3] = fmaxf(mx[3], s0.w);
      mx[4] = fmaxf(mx[4], s1.x); mx[5] = fmaxf(mx[5], s1.y);
      mx[6] = fmaxf(mx[6], s1.z); mx[7] = fmaxf(mx[7], s1.w);
    }
    #pragma unroll
    for (int off = 32; off >= 1; off >>= 1)
      #pragma unroll
      for (int h = 0; h < NH; ++h) mx[h] = fmaxf(mx[h], __shfl_xor(mx[h], off));
    if (lane == 0) {
      #pragma unroll
      for (int h = 0; h < NH; ++h) red[wave][h] = mx[h];
    }
    __syncthreads();
    #pragma unroll
    for (int h = 0; h < NH; ++h)
      mx[h] = fmaxf(fmaxf(red[0][h], red[1][h]), fmaxf(red[2][h], red[3][h]));
    __syncthreads();

    float sm[NH];
    #pragma unroll
    for (int h = 0; h < NH; ++h) sm[h] = 0.f;
    for (int i = s + tid; i < e; i += 256) {
      float4 s0 = *(const float4*)(scores + (size_t)i * NH);
      float4 s1 = *(const float4*)(scores + (size_t)i * NH + 4);
      sm[0] += __expf(s0.x - mx[0]); sm[1] += __expf(s0.y - mx[1]);
      sm[2] += __expf(s0.z - mx[2]); sm[3] += __expf(s0.w - mx[3]);
      sm[4] += __expf(s1.x - mx[4]); sm[5] += __expf(s1.y - mx[5]);
      sm[6] += __expf(s1.z - mx[6]); sm[7] += __expf(s1.w - mx[7]);
    }
    #pragma unroll
    for (int off = 32; off >= 1; off >>= 1)
      #pragma unroll
      for (int h = 0; h < NH; ++h) sm[h] += __shfl_xor(sm[h], off);
    if (lane == 0) {
      #pragma unroll
      for (int h = 0; h < NH; ++h) red[wave][h] = sm[h];
    }
    __syncthreads();
    m0 = mx[h0]; m1 = mx[h1];
    ri0 = 1.f / (red[0][h0] + red[1][h0] + red[2][h0] + red[3][h0]);
    ri1 = 1.f / (red[0][h1] + red[1][h1] + red[2][h1] + red[3][h1]);
  }

  float vsum[4] = {0.f, 0.f, 0.f, 0.f};

  // T14: preload first chunk; inside the loop, issue next chunk's loads
  // before the current chunk's weight reads + MFMA.
  f16x8 aC[4];
  {
    int arow = s + lo;
    int ar = arow < V ? arow : V - 1;
    #pragma unroll
    for (int kb = 0; kb < 4; ++kb)
      aC[kb] = *(const f16x8*)(ht + (size_t)ar * HID + kb * 32 + hi * 8);
  }

  for (int cb = s; cb < e; cb += 16) {
    // Issue next chunk's A-frag loads (clamped; harmless past e).
    f16x8 aN[4];
    {
      int nrow = cb + 16 + lo;
      int nr = nrow < V ? nrow : V - 1;
      #pragma unroll
      for (int kb = 0; kb < 4; ++kb)
        aN[kb] = *(const f16x8*)(ht + (size_t)nr * HID + kb * 32 + hi * 8);
    }

    int wr = cb + hi * 4;
    float wv[2][4];
    if (use_lds) {
      #pragma unroll
      for (int r = 0; r < 4; ++r) {
        int row = wr + r;
        bool in = row < e;
        int rel = in ? (row - s) : 0;
        wv[0][r] = in ? lW[rel * NH + h0] : 0.f;
        wv[1][r] = in ? lW[rel * NH + h1] : 0.f;
      }
    } else {
      #pragma unroll
      for (int r = 0; r < 4; ++r) {
        int row = wr + r;
        bool in = row < e;
        float sc0 = in ? scores[(size_t)row * NH + h0] : 0.f;
        float sc1 = in ? scores[(size_t)row * NH + h1] : 0.f;
        wv[0][r] = in ? __expf(sc0 - m0) * ri0 : 0.f;
        wv[1][r] = in ? __expf(sc1 - m1) * ri1 : 0.f;
      }
    }
    #pragma unroll
    for (int j = 0; j < 4; ++j) {
      f32x4 acc = {0.f, 0.f, 0.f, 0.f};
      #pragma unroll
      for (int kb = 0; kb < 4; ++kb)
        acc = __builtin_amdgcn_mfma_f32_16x16x32_f16(aC[kb], b[j][kb], acc, 0, 0, 0);
      const float* wvp = wv[j >> 1];
      float v = 0.f;
      #pragma unroll
      for (int r = 0; r < 4; ++r) v += fmaxf(acc[r], 0.f) * wvp[r];
      vsum[j] += v;
    }
    #pragma unroll
    for (int kb = 0; kb < 4; ++kb) aC[kb] = aN[kb];
  }

  #pragma unroll
  for (int j = 0; j < 4; ++j) {
    float v = vsum[j];
    v += __shfl_xor(v, 16);
    v += __shfl_xor(v, 32);
    if (lane < 16) out[(size_t)g * GD + (wave * 4 + j) * 16 + lo] = v;
  }
}

// ---- fallback path (ws too small for ht): old stats + recompute kernels ----
__global__ __launch_bounds__(64) void k_stats(
    float* __restrict__ scores, const int* __restrict__ gs) {
  int g = blockIdx.x;
  int lane = threadIdx.x;
  int s = gs[g], e = gs[g + 1];
  if (e <= s) return;
  float mx[NH];
  #pragma unroll
  for (int h = 0; h < NH; ++h) mx[h] = -1e30f;
  for (int i = s + lane; i < e; i += 64) {
    float4 s0 = *(const float4*)(scores + (size_t)i * NH);
    float4 s1 = *(const float4*)(scores + (size_t)i * NH + 4);
    mx[0] = fmaxf(mx[0], s0.x); mx[1] = fmaxf(mx[1], s0.y);
    mx[2] = fmaxf(mx[2], s0.z); mx[3] = fmaxf(mx[3], s0.w);
    mx[4] = fmaxf(mx[4], s1.x); mx[5] = fmaxf(mx[5], s1.y);
    mx[6] = fmaxf(mx[6], s1.z); mx[7] = fmaxf(mx[7], s1.w);
  }
  #pragma unroll
  for (int off = 32; off >= 1; off >>= 1)
    #pragma unroll
    for (int h = 0; h < NH; ++h) mx[h] = fmaxf(mx[h], __shfl_xor(mx[h], off));
  float sm[NH];
  #pragma unroll
  for (int h = 0; h < NH; ++h) sm[h] = 0.f;
  for (int i = s + lane; i < e; i += 64) {
    float4 s0 = *(const float4*)(scores + (size_t)i * NH);
    float4 s1 = *(const float4*)(scores + (size_t)i * NH + 4);
    sm[0] += __expf(s0.x - mx[0]); sm[1] += __expf(s0.y - mx[1]);
    sm[2] += __expf(s0.z - mx[2]); sm[3] += __expf(s0.w - mx[3]);
    sm[4] += __expf(s1.x - mx[4]); sm[5] += __expf(s1.y - mx[5]);
    sm[6] += __expf(s1.z - mx[6]); sm[7] += __expf(s1.w - mx[7]);
  }
  #pragma unroll
  for (int off = 32; off >= 1; off >>= 1)
    #pragma unroll
    for (int h = 0; h < NH; ++h) sm[h] += __shfl_xor(sm[h], off);
  float rinv[NH];
  #pragma unroll
  for (int h = 0; h < NH; ++h) rinv[h] = 1.f / sm[h];
  for (int i = s + lane; i < e; i += 64) {
    float4 s0 = *(const float4*)(scores + (size_t)i * NH);
    float4 s1 = *(const float4*)(scores + (size_t)i * NH + 4);
    s0.x = __expf(s0.x - mx[0]) * rinv[0]; s0.y = __expf(s0.y - mx[1]) * rinv[1];
    s0.z = __expf(s0.z - mx[2]) * rinv[2]; s0.w = __expf(s0.w - mx[3]) * rinv[3];
    s1.x = __expf(s1.x - mx[4]) * rinv[4]; s1.y = __expf(s1.y - mx[5]) * rinv[5];
    s1.z = __expf(s1.z - mx[6]) * rinv[6]; s1.w = __expf(s1.w - mx[7]) * rinv[7];
    *(float4*)(scores + (size_t)i * NH) = s0;
    *(float4*)(scores + (size_t)i * NH + 4) = s1;
  }
}

__global__ __launch_bounds__(256, 2) void k_transform2(
    const float* __restrict__ E, int V,
    const f16* __restrict__ W1tp, const f16* __restrict__ W2tp,
    const float* __restrict__ w, const int* __restrict__ gs,
    float* __restrict__ out) {
  __shared__ f16 hl[16][HID + 8];
  const int g = blockIdx.x;
  const int wave = threadIdx.x >> 6;
  const int lane = threadIdx.x & 63;
  const int hi = lane >> 4;
  const int lo = lane & 15;
  const int s = gs[g], e = gs[g + 1];

  f16x8 b[4][4];
  #pragma unroll
  for (int j = 0; j < 4; ++j)
    #pragma unroll
    for (int kb = 0; kb < 4; ++kb)
      b[j][kb] = *(const f16x8*)(
          W2tp + ((size_t)(kb * 16 + wave * 4 + j) * 64 + lane) * 8);

  float vsum[4] = {0.f, 0.f, 0.f, 0.f};

  for (int cb = s; cb < e; cb += 16) {
    int arow = cb + lo;
    int ar = arow < V ? arow : V - 1;
    f16x8 a[8];
    const float* ep = E + (size_t)ar * VD + hi * 8;
    #pragma unroll
    for (int kb = 0; kb < 8; ++kb) a[kb] = load_a_frag(ep + kb * 32);

    __syncthreads();
    #pragma unroll
    for (int nn = 0; nn < 2; ++nn) {
      int n = wave * 2 + nn;
      f32x4 acc = {0.f, 0.f, 0.f, 0.f};
      #pragma unroll
      for (int kb = 0; kb < 8; ++kb) {
        f16x8 bb = *(const f16x8*)(W1tp + ((size_t)(kb * 8 + n) * 64 + lane) * 8);
        acc = __builtin_amdgcn_mfma_f32_16x16x32_f16(a[kb], bb, acc, 0, 0, 0);
      }
      #pragma unroll
      for (int r = 0; r < 4; ++r)
        hl[hi * 4 + r][n * 16 + lo] = (f16)fmaxf(acc[r], 0.f);
    }
    __syncthreads();

    int wr = cb + hi * 4;
    float wv[2][4];
    #pragma unroll
    for (int hh = 0; hh < 2; ++hh) {
      int head = wave * 2 + hh;
      #pragma unroll
      for (int r = 0; r < 4; ++r) {
        int row = wr + r;
        wv[hh][r] = (row < e) ? w[(size_t)row * NH + head] : 0.f;
      }
    }
    f16x8 a2[4];
    #pragma unroll
    for (int kb = 0; kb < 4; ++kb)
      a2[kb] = *(const f16x8*)&hl[lo][kb * 32 + hi * 8];
    #pragma unroll
    for (int j = 0; j < 4; ++j) {
      f32x4 acc = {0.f, 0.f, 0.f, 0.f};
      #pragma unroll
      for (int kb = 0; kb < 4; ++kb)
        acc = __builtin_amdgcn_mfma_f32_16x16x32_f16(a2[kb], b[j][kb], acc, 0, 0, 0);
      const float* wvp = wv[j >> 1];
      float v = 0.f;
      #pragma unroll
      for (int r = 0; r < 4; ++r) v += fmaxf(acc[r], 0.f) * wvp[r];
      vsum[j] += v;
    }
  }

  #pragma unroll
  for (int j = 0; j < 4; ++j) {
    float v = vsum[j];
    v += __shfl_xor(v, 16);
    v += __shfl_xor(v, 32);
    if (lane < 16) out[(size_t)g * GD + (wave * 4 + j) * 16 + lo] = v;
  }
}

extern "C" void kernel_launch(void* const* d_in, const int* in_sizes, int n_in,
                              void* d_out, int out_size, void* d_ws, size_t ws_size,
                              hipStream_t stream) {
  const float* E   = (const float*)d_in[0];
  const int*   map = (const int*)d_in[1];
  const float* w1s = (const float*)d_in[3];
  const float* w2s = (const float*)d_in[4];
  const float* w1t = (const float*)d_in[5];
  const float* w2t = (const float*)d_in[6];
  const int V = in_sizes[0] / VD;
  const int G = NGRAPH;

  char* ws = (char*)d_ws;
  size_t off = 0;
  float* scores = (float*)(ws + off); off += (size_t)V * NH * 4;
  int* gs = (int*)(ws + off); off += (size_t)(G + 1) * 4;
  off = (off + 255) & ~(size_t)255;
  f16* W1sp = (f16*)(ws + off); off += (size_t)VD * HID * 2;
  f16* W1tp = (f16*)(ws + off); off += (size_t)VD * HID * 2;
  f16* W2tp = (f16*)(ws + off); off += (size_t)HID * GD * 2;
  f16* W2sp = (f16*)(ws + off); off += (size_t)HID * 16 * 2;
  off = (off + 255) & ~(size_t)255;
  f16* ht = (f16*)(ws + off);
  const size_t need_fused = off + (size_t)V * HID * 2;
  const bool fused = ws_size >= need_fused;

  k_prep<<<65, 256, 0, stream>>>(w1s, w1t, w2t, w2s, map,
                                 W1sp, W1tp, W2tp, W2sp, gs, V, G);

  const int ntiles = (V + RT - 1) / RT;
  const int grid1 = (ntiles + 3) / 4;
  k_stage1<<<grid1, 512, 0, stream>>>(
      E, V, ntiles, W1sp, W2sp, W1tp, scores, fused ? ht : nullptr);

  if (fused) {
    k_graph<<<G, 256, 0, stream>>>(ht, scores, W2tp, gs, (float*)d_out, V);
  } else {
    k_stats<<<G, 64, 0, stream>>>(scores, gs);
    k_transform2<<<G, 256, 0, stream>>>(E, V, W1tp, W2tp, scores, gs,
                                        (float*)d_out);
  }
}

// Round 10
// 274.866 us; speedup vs baseline: 1.2404x; 1.1743x over previous
//
#include <hip/hip_runtime.h>
#include <hip/hip_fp16.h>

#define VD 256
#define HID 128
#define GD 256
#define NH 8
#define NGRAPH 4000   // num_graphs only available as device scalar; grid needs host value.
#define RT 64         // rows per k_stage1 tile
#define MAXROWS 512   // k_graph LDS score-staging cap (avg graph = 125 rows)

typedef _Float16 f16;
typedef f16 f16x4 __attribute__((ext_vector_type(4)));
typedef f16 f16x8 __attribute__((ext_vector_type(8)));
typedef float f32x4 __attribute__((ext_vector_type(4)));

__device__ __forceinline__ f16x8 load_a_frag(const float* p) {
  float4 p0 = *(const float4*)(p);
  float4 p1 = *(const float4*)(p + 4);
  f16x8 v;
  v[0] = (f16)p0.x; v[1] = (f16)p0.y; v[2] = (f16)p0.z; v[3] = (f16)p0.w;
  v[4] = (f16)p1.x; v[5] = (f16)p1.y; v[6] = (f16)p1.z; v[7] = (f16)p1.w;
  return v;
}

// Pack B operand [K][Nsrc] f32 -> MFMA B-fragment order f16.
// frag (kb,nb): lane l, elem i holds B[kb*32 + (l>>4)*8 + i][nb*16 + (l&15)]
__device__ __forceinline__ void pack_b_dev(const float* __restrict__ src,
                                           f16* __restrict__ dst,
                                           int K, int Nsrc, int Ndst, int t) {
  int NB = Ndst / 16, KB = K / 32;
  int total = KB * NB * 64;
  if (t >= total) return;
  int lane = t & 63;
  int frag = t >> 6;
  int nb = frag % NB, kb = frag / NB;
  int col = nb * 16 + (lane & 15);
  int krow = kb * 32 + (lane >> 4) * 8;
  f16x8 o;
  #pragma unroll
  for (int i = 0; i < 8; ++i) {
    float v = (col < Nsrc) ? src[(size_t)(krow + i) * Nsrc + col] : 0.0f;
    o[i] = (f16)v;
  }
  *(f16x8*)(dst + (size_t)t * 8) = o;
}

// One launch for all weight packing + segment bounds.
__global__ __launch_bounds__(256) void k_prep(
    const float* __restrict__ w1s, const float* __restrict__ w1t,
    const float* __restrict__ w2t, const float* __restrict__ w2s,
    const int* __restrict__ map,
    f16* __restrict__ W1sp, f16* __restrict__ W1tp,
    f16* __restrict__ W2tp, f16* __restrict__ W2sp,
    int* __restrict__ gs, int V, int G) {
  int b = blockIdx.x;
  int tid = threadIdx.x;
  if (b < 16) {
    pack_b_dev(w1s, W1sp, VD, HID, HID, b * 256 + tid);
  } else if (b < 32) {
    pack_b_dev(w1t, W1tp, VD, HID, HID, (b - 16) * 256 + tid);
  } else if (b < 48) {
    pack_b_dev(w2t, W2tp, HID, GD, GD, (b - 32) * 256 + tid);
  } else if (b == 48) {
    pack_b_dev(w2s, W2sp, HID, NH, 16, tid);
  } else {
    int g = (b - 49) * 256 + tid;
    if (g > G) return;
    int lo = 0, hi = V;
    while (lo < hi) {
      int mid = (lo + hi) >> 1;
      if (map[mid] < g) lo = mid + 1; else hi = mid;
    }
    gs[g] = lo;
  }
}

// Phase 1: one pass over E. Grid-stride over 64-row tiles (4 tiles/block):
// B-frags register-resident across tiles; next tile's E prefetched into
// registers while current tile runs MFMA.
// waves_per_eu pinned to (4,4): LDS caps at 2 blocks/CU anyway; a higher
// occupancy target makes the allocator choose 64 VGPR and spill Bs/Bt
// (R5: +350 MB scratch traffic, 2.5x dur).
__global__ __attribute__((amdgpu_flat_work_group_size(512, 512),
                          amdgpu_waves_per_eu(4, 4))) void k_stage1(
    const float* __restrict__ E, int V, int ntiles,
    const f16* __restrict__ W1sp, const f16* __restrict__ W2sp,
    const f16* __restrict__ W1tp,
    float* __restrict__ scores, f16* __restrict__ ht) {
  __shared__ __attribute__((aligned(16))) f16 lE[RT][VD + 8];
  __shared__ __attribute__((aligned(16))) f16 lH[RT][HID + 8];
  __shared__ __attribute__((aligned(16))) f16 lT[RT][HID + 8];
  const int tid = threadIdx.x;
  const int wave = tid >> 6;
  const int lane = tid & 63;
  const int hi = lane >> 4;
  const int lo = lane & 15;
  const int srow = tid >> 6;        // staging: 8 chunks/thread
  const int scol = (tid & 63) * 4;

  // B fragments: loaded once per block, register-resident for all tiles.
  f16x8 Bs[8], Bt[8];
  #pragma unroll
  for (int kb = 0; kb < 8; ++kb) {
    Bs[kb] = *(const f16x8*)(W1sp + ((size_t)(kb * 8 + wave) * 64 + lane) * 8);
    Bt[kb] = *(const f16x8*)(W1tp + ((size_t)(kb * 8 + wave) * 64 + lane) * 8);
  }

  int t = blockIdx.x;
  if (t >= ntiles) return;
  const int stride = gridDim.x;

  float4 pf[8];
  {
    const int r0 = t * RT;
    #pragma unroll
    for (int p = 0; p < 8; ++p) {
      int grow = r0 + p * 8 + srow;
      pf[p] = (grow < V) ? *(const float4*)(E + (size_t)grow * VD + scol)
                         : make_float4(0.f, 0.f, 0.f, 0.f);
    }
  }

  while (t < ntiles) {
    const int r0 = t * RT;
    // Write prefetched tile -> LDS (convert f32->f16 once).
    #pragma unroll
    for (int p = 0; p < 8; ++p) {
      f16x4 h;
      h[0] = (f16)pf[p].x; h[1] = (f16)pf[p].y;
      h[2] = (f16)pf[p].z; h[3] = (f16)pf[p].w;
      *(f16x4*)&lE[p * 8 + srow][scol] = h;
    }
    // Issue next tile's loads (consumed at next iteration's LDS write).
    const int tn = t + stride;
    if (tn < ntiles) {
      const int rn = tn * RT;
      #pragma unroll
      for (int p = 0; p < 8; ++p) {
        int grow = rn + p * 8 + srow;
        pf[p] = (grow < V) ? *(const float4*)(E + (size_t)grow * VD + scol)
                           : make_float4(0.f, 0.f, 0.f, 0.f);
      }
    }
    __syncthreads();   // lE ready; lH/lT free

    // Stage 1: h_s/h_t col-block `wave` for all 4 m-tiles.
    #pragma unroll
    for (int m = 0; m < 4; ++m) {
      f32x4 as = {0.f, 0.f, 0.f, 0.f};
      f32x4 at = {0.f, 0.f, 0.f, 0.f};
      #pragma unroll
      for (int kb = 0; kb < 8; ++kb) {
        f16x8 a = *(const f16x8*)&lE[m * 16 + lo][kb * 32 + hi * 8];
        as = __builtin_amdgcn_mfma_f32_16x16x32_f16(a, Bs[kb], as, 0, 0, 0);
        at = __builtin_amdgcn_mfma_f32_16x16x32_f16(a, Bt[kb], at, 0, 0, 0);
      }
      #pragma unroll
      for (int r = 0; r < 4; ++r) {
        lH[m * 16 + hi * 4 + r][wave * 16 + lo] = (f16)fmaxf(as[r], 0.f);
        if (ht != nullptr)
          lT[m * 16 + hi * 4 + r][wave * 16 + lo] = (f16)fmaxf(at[r], 0.f);
      }
    }
    __syncthreads();   // lH/lT ready; lE reads done

    // ht -> global FIRST (fire-and-forget stores overlap the scores MFMA).
    if (ht != nullptr) {
      #pragma unroll
      for (int p = 0; p < 2; ++p) {
        int c = p * 512 + tid;
        int row = c >> 4;
        int col = (c & 15) * 8;
        int grow = r0 + row;
        if (grow < V)
          *(f16x8*)(ht + (size_t)grow * HID + col) = *(const f16x8*)&lT[row][col];
      }
    }

    // Stage 2 (waves 0-3): scores = h_s @ W2s for m-block = wave.
    if (wave < 4) {
      f16x8 a2[4];
      #pragma unroll
      for (int kb = 0; kb < 4; ++kb)
        a2[kb] = *(const f16x8*)&lH[wave * 16 + lo][kb * 32 + hi * 8];
      f32x4 acc = {0.f, 0.f, 0.f, 0.f};
      #pragma unroll
      for (int kb = 0; kb < 4; ++kb) {
        f16x8 b = *(const f16x8*)(W2sp + ((size_t)kb * 64 + lane) * 8);
        acc = __builtin_amdgcn_mfma_f32_16x16x32_f16(a2[kb], b, acc, 0, 0, 0);
      }
      if (lo < NH) {
        #pragma unroll
        for (int r = 0; r < 4; ++r) {
          int row = r0 + wave * 16 + hi * 4 + r;
          if (row < V) scores[(size_t)row * NH + lo] = acc[r];
        }
      }
    }
    t = tn;
  }
}

// Phase 2 fused with softmax stats: per-graph WG (4 waves). Graph's scores
// staged to LDS once (<=MAXROWS rows), stats computed from LDS, then LDS is
// overwritten in place with final softmax weights; main loop reads weights
// from LDS. Wave w owns cols [w*64, w*64+64); W2t B-frags in registers.
// T14 issue-early prefetch of the next ht chunk; waves_per_eu(3,3) gives the
// allocator a 170-VGPR budget so the prefetch (b64+aC16+aN16+misc ~ 140)
// does NOT spill (R9: at the 128 budget of (4,4) it spilled, +59 us).
__global__ __attribute__((amdgpu_flat_work_group_size(256, 256),
                          amdgpu_waves_per_eu(3, 3))) void k_graph(
    const f16* __restrict__ ht, const float* __restrict__ scores,
    const f16* __restrict__ W2tp, const int* __restrict__ gs,
    float* __restrict__ out, int V) {
  __shared__ float red[4][NH];
  __shared__ float lW[MAXROWS * NH];   // 16 KB
  const int g = blockIdx.x;
  const int tid = threadIdx.x;
  const int wave = tid >> 6;
  const int lane = tid & 63;
  const int hi = lane >> 4;
  const int lo = lane & 15;
  const int s = gs[g], e = gs[g + 1];
  const int n = e - s;

  if (n <= 0) {
    out[(size_t)g * GD + tid] = 0.f;
    return;
  }

  f16x8 b[4][4];
  #pragma unroll
  for (int j = 0; j < 4; ++j)
    #pragma unroll
    for (int kb = 0; kb < 4; ++kb)
      b[j][kb] = *(const f16x8*)(
          W2tp + ((size_t)(kb * 16 + wave * 4 + j) * 64 + lane) * 8);

  const int h0 = wave * 2, h1 = wave * 2 + 1;
  float m0, m1, ri0, ri1;
  const bool use_lds = (n <= MAXROWS);

  if (use_lds) {
    // Stage scores -> LDS (coalesced float4; n*2 chunks).
    for (int c = tid; c < n * 2; c += 256)
      *(float4*)&lW[c * 4] = *(const float4*)(scores + (size_t)s * NH + c * 4);
    __syncthreads();

    // Per-head max from LDS.
    float mx[NH];
    #pragma unroll
    for (int h = 0; h < NH; ++h) mx[h] = -1e30f;
    for (int i = tid; i < n; i += 256) {
      #pragma unroll
      for (int h = 0; h < NH; ++h) mx[h] = fmaxf(mx[h], lW[i * NH + h]);
    }
    #pragma unroll
    for (int off = 32; off >= 1; off >>= 1)
      #pragma unroll
      for (int h = 0; h < NH; ++h) mx[h] = fmaxf(mx[h], __shfl_xor(mx[h], off));
    if (lane == 0) {
      #pragma unroll
      for (int h = 0; h < NH; ++h) red[wave][h] = mx[h];
    }
    __syncthreads();
    #pragma unroll
    for (int h = 0; h < NH; ++h)
      mx[h] = fmaxf(fmaxf(red[0][h], red[1][h]), fmaxf(red[2][h], red[3][h]));
    __syncthreads();

    // Per-head sum of exp from LDS.
    float sm[NH];
    #pragma unroll
    for (int h = 0; h < NH; ++h) sm[h] = 0.f;
    for (int i = tid; i < n; i += 256) {
      #pragma unroll
      for (int h = 0; h < NH; ++h) sm[h] += __expf(lW[i * NH + h] - mx[h]);
    }
    #pragma unroll
    for (int off = 32; off >= 1; off >>= 1)
      #pragma unroll
      for (int h = 0; h < NH; ++h) sm[h] += __shfl_xor(sm[h], off);
    if (lane == 0) {
      #pragma unroll
      for (int h = 0; h < NH; ++h) red[wave][h] = sm[h];
    }
    __syncthreads();

    float rinv[NH];
    #pragma unroll
    for (int h = 0; h < NH; ++h)
      rinv[h] = 1.f / (red[0][h] + red[1][h] + red[2][h] + red[3][h]);

    // Overwrite LDS scores with final weights.
    for (int i = tid; i < n; i += 256) {
      #pragma unroll
      for (int h = 0; h < NH; ++h)
        lW[i * NH + h] = __expf(lW[i * NH + h] - mx[h]) * rinv[h];
    }
    __syncthreads();
    m0 = mx[h0]; m1 = mx[h1]; ri0 = rinv[h0]; ri1 = rinv[h1];
  } else {
    // Fallback: stats straight from global (rare: n > MAXROWS).
    float mx[NH];
    #pragma unroll
    for (int h = 0; h < NH; ++h) mx[h] = -1e30f;
    for (int i = s + tid; i < e; i += 256) {
      float4 s0 = *(const float4*)(scores + (size_t)i * NH);
      float4 s1 = *(const float4*)(scores + (size_t)i * NH + 4);
      mx[0] = fmaxf(mx[0], s0.x); mx[1] = fmaxf(mx[1], s0.y);
      mx[2] = fmaxf(mx[2], s0.z); mx[3] = fmaxf(mx[3], s0.w);
      mx[4] = fmaxf(mx[4], s1.x); mx[5] = fmaxf(mx[5], s1.y);
      mx[6] = fmaxf(mx[6], s1.z); mx[7] = fmaxf(mx[7], s1.w);
    }
    #pragma unroll
    for (int off = 32; off >= 1; off >>= 1)
      #pragma unroll
      for (int h = 0; h < NH; ++h) mx[h] = fmaxf(mx[h], __shfl_xor(mx[h], off));
    if (lane == 0) {
      #pragma unroll
      for (int h = 0; h < NH; ++h) red[wave][h] = mx[h];
    }
    __syncthreads();
    #pragma unroll
    for (int h = 0; h < NH; ++h)
      mx[h] = fmaxf(fmaxf(red[0][h], red[1][h]), fmaxf(red[2][h], red[3][h]));
    __syncthreads();

    float sm[NH];
    #pragma unroll
    for (int h = 0; h < NH; ++h) sm[h] = 0.f;
    for (int i = s + tid; i < e; i += 256) {
      float4 s0 = *(const float4*)(scores + (size_t)i * NH);
      float4 s1 = *(const float4*)(scores + (size_t)i * NH + 4);
      sm[0] += __expf(s0.x - mx[0]); sm[1] += __expf(s0.y - mx[1]);
      sm[2] += __expf(s0.z - mx[2]); sm[3] += __expf(s0.w - mx[3]);
      sm[4] += __expf(s1.x - mx[4]); sm[5] += __expf(s1.y - mx[5]);
      sm[6] += __expf(s1.z - mx[6]); sm[7] += __expf(s1.w - mx[7]);
    }
    #pragma unroll
    for (int off = 32; off >= 1; off >>= 1)
      #pragma unroll
      for (int h = 0; h < NH; ++h) sm[h] += __shfl_xor(sm[h], off);
    if (lane == 0) {
      #pragma unroll
      for (int h = 0; h < NH; ++h) red[wave][h] = sm[h];
    }
    __syncthreads();
    m0 = mx[h0]; m1 = mx[h1];
    ri0 = 1.f / (red[0][h0] + red[1][h0] + red[2][h0] + red[3][h0]);
    ri1 = 1.f / (red[0][h1] + red[1][h1] + red[2][h1] + red[3][h1]);
  }

  float vsum[4] = {0.f, 0.f, 0.f, 0.f};

  // T14: preload first chunk; inside the loop, issue next chunk's loads
  // before the current chunk's weight reads + MFMA.
  f16x8 aC[4];
  {
    int arow = s + lo;
    int ar = arow < V ? arow : V - 1;
    #pragma unroll
    for (int kb = 0; kb < 4; ++kb)
      aC[kb] = *(const f16x8*)(ht + (size_t)ar * HID + kb * 32 + hi * 8);
  }

  for (int cb = s; cb < e; cb += 16) {
    // Issue next chunk's A-frag loads (clamped; harmless past e).
    f16x8 aN[4];
    {
      int nrow = cb + 16 + lo;
      int nr = nrow < V ? nrow : V - 1;
      #pragma unroll
      for (int kb = 0; kb < 4; ++kb)
        aN[kb] = *(const f16x8*)(ht + (size_t)nr * HID + kb * 32 + hi * 8);
    }

    int wr = cb + hi * 4;
    float wv[2][4];
    if (use_lds) {
      #pragma unroll
      for (int r = 0; r < 4; ++r) {
        int row = wr + r;
        bool in = row < e;
        int rel = in ? (row - s) : 0;
        wv[0][r] = in ? lW[rel * NH + h0] : 0.f;
        wv[1][r] = in ? lW[rel * NH + h1] : 0.f;
      }
    } else {
      #pragma unroll
      for (int r = 0; r < 4; ++r) {
        int row = wr + r;
        bool in = row < e;
        float sc0 = in ? scores[(size_t)row * NH + h0] : 0.f;
        float sc1 = in ? scores[(size_t)row * NH + h1] : 0.f;
        wv[0][r] = in ? __expf(sc0 - m0) * ri0 : 0.f;
        wv[1][r] = in ? __expf(sc1 - m1) * ri1 : 0.f;
      }
    }
    #pragma unroll
    for (int j = 0; j < 4; ++j) {
      f32x4 acc = {0.f, 0.f, 0.f, 0.f};
      #pragma unroll
      for (int kb = 0; kb < 4; ++kb)
        acc = __builtin_amdgcn_mfma_f32_16x16x32_f16(aC[kb], b[j][kb], acc, 0, 0, 0);
      const float* wvp = wv[j >> 1];
      float v = 0.f;
      #pragma unroll
      for (int r = 0; r < 4; ++r) v += fmaxf(acc[r], 0.f) * wvp[r];
      vsum[j] += v;
    }
    #pragma unroll
    for (int kb = 0; kb < 4; ++kb) aC[kb] = aN[kb];
  }

  #pragma unroll
  for (int j = 0; j < 4; ++j) {
    float v = vsum[j];
    v += __shfl_xor(v, 16);
    v += __shfl_xor(v, 32);
    if (lane < 16) out[(size_t)g * GD + (wave * 4 + j) * 16 + lo] = v;
  }
}

// ---- fallback path (ws too small for ht): old stats + recompute kernels ----
__global__ __launch_bounds__(64) void k_stats(
    float* __restrict__ scores, const int* __restrict__ gs) {
  int g = blockIdx.x;
  int lane = threadIdx.x;
  int s = gs[g], e = gs[g + 1];
  if (e <= s) return;
  float mx[NH];
  #pragma unroll
  for (int h = 0; h < NH; ++h) mx[h] = -1e30f;
  for (int i = s + lane; i < e; i += 64) {
    float4 s0 = *(const float4*)(scores + (size_t)i * NH);
    float4 s1 = *(const float4*)(scores + (size_t)i * NH + 4);
    mx[0] = fmaxf(mx[0], s0.x); mx[1] = fmaxf(mx[1], s0.y);
    mx[2] = fmaxf(mx[2], s0.z); mx[3] = fmaxf(mx[3], s0.w);
    mx[4] = fmaxf(mx[4], s1.x); mx[5] = fmaxf(mx[5], s1.y);
    mx[6] = fmaxf(mx[6], s1.z); mx[7] = fmaxf(mx[7], s1.w);
  }
  #pragma unroll
  for (int off = 32; off >= 1; off >>= 1)
    #pragma unroll
    for (int h = 0; h < NH; ++h) mx[h] = fmaxf(mx[h], __shfl_xor(mx[h], off));
  float sm[NH];
  #pragma unroll
  for (int h = 0; h < NH; ++h) sm[h] = 0.f;
  for (int i = s + lane; i < e; i += 64) {
    float4 s0 = *(const float4*)(scores + (size_t)i * NH);
    float4 s1 = *(const float4*)(scores + (size_t)i * NH + 4);
    sm[0] += __expf(s0.x - mx[0]); sm[1] += __expf(s0.y - mx[1]);
    sm[2] += __expf(s0.z - mx[2]); sm[3] += __expf(s0.w - mx[3]);
    sm[4] += __expf(s1.x - mx[4]); sm[5] += __expf(s1.y - mx[5]);
    sm[6] += __expf(s1.z - mx[6]); sm[7] += __expf(s1.w - mx[7]);
  }
  #pragma unroll
  for (int off = 32; off >= 1; off >>= 1)
    #pragma unroll
    for (int h = 0; h < NH; ++h) sm[h] += __shfl_xor(sm[h], off);
  float rinv[NH];
  #pragma unroll
  for (int h = 0; h < NH; ++h) rinv[h] = 1.f / sm[h];
  for (int i = s + lane; i < e; i += 64) {
    float4 s0 = *(const float4*)(scores + (size_t)i * NH);
    float4 s1 = *(const float4*)(scores + (size_t)i * NH + 4);
    s0.x = __expf(s0.x - mx[0]) * rinv[0]; s0.y = __expf(s0.y - mx[1]) * rinv[1];
    s0.z = __expf(s0.z - mx[2]) * rinv[2]; s0.w = __expf(s0.w - mx[3]) * rinv[3];
    s1.x = __expf(s1.x - mx[4]) * rinv[4]; s1.y = __expf(s1.y - mx[5]) * rinv[5];
    s1.z = __expf(s1.z - mx[6]) * rinv[6]; s1.w = __expf(s1.w - mx[7]) * rinv[7];
    *(float4*)(scores + (size_t)i * NH) = s0;
    *(float4*)(scores + (size_t)i * NH + 4) = s1;
  }
}

__global__ __launch_bounds__(256, 2) void k_transform2(
    const float* __restrict__ E, int V,
    const f16* __restrict__ W1tp, const f16* __restrict__ W2tp,
    const float* __restrict__ w, const int* __restrict__ gs,
    float* __restrict__ out) {
  __shared__ f16 hl[16][HID + 8];
  const int g = blockIdx.x;
  const int wave = threadIdx.x >> 6;
  const int lane = threadIdx.x & 63;
  const int hi = lane >> 4;
  const int lo = lane & 15;
  const int s = gs[g], e = gs[g + 1];

  f16x8 b[4][4];
  #pragma unroll
  for (int j = 0; j < 4; ++j)
    #pragma unroll
    for (int kb = 0; kb < 4; ++kb)
      b[j][kb] = *(const f16x8*)(
          W2tp + ((size_t)(kb * 16 + wave * 4 + j) * 64 + lane) * 8);

  float vsum[4] = {0.f, 0.f, 0.f, 0.f};

  for (int cb = s; cb < e; cb += 16) {
    int arow = cb + lo;
    int ar = arow < V ? arow : V - 1;
    f16x8 a[8];
    const float* ep = E + (size_t)ar * VD + hi * 8;
    #pragma unroll
    for (int kb = 0; kb < 8; ++kb) a[kb] = load_a_frag(ep + kb * 32);

    __syncthreads();
    #pragma unroll
    for (int nn = 0; nn < 2; ++nn) {
      int n = wave * 2 + nn;
      f32x4 acc = {0.f, 0.f, 0.f, 0.f};
      #pragma unroll
      for (int kb = 0; kb < 8; ++kb) {
        f16x8 bb = *(const f16x8*)(W1tp + ((size_t)(kb * 8 + n) * 64 + lane) * 8);
        acc = __builtin_amdgcn_mfma_f32_16x16x32_f16(a[kb], bb, acc, 0, 0, 0);
      }
      #pragma unroll
      for (int r = 0; r < 4; ++r)
        hl[hi * 4 + r][n * 16 + lo] = (f16)fmaxf(acc[r], 0.f);
    }
    __syncthreads();

    int wr = cb + hi * 4;
    float wv[2][4];
    #pragma unroll
    for (int hh = 0; hh < 2; ++hh) {
      int head = wave * 2 + hh;
      #pragma unroll
      for (int r = 0; r < 4; ++r) {
        int row = wr + r;
        wv[hh][r] = (row < e) ? w[(size_t)row * NH + head] : 0.f;
      }
    }
    f16x8 a2[4];
    #pragma unroll
    for (int kb = 0; kb < 4; ++kb)
      a2[kb] = *(const f16x8*)&hl[lo][kb * 32 + hi * 8];
    #pragma unroll
    for (int j = 0; j < 4; ++j) {
      f32x4 acc = {0.f, 0.f, 0.f, 0.f};
      #pragma unroll
      for (int kb = 0; kb < 4; ++kb)
        acc = __builtin_amdgcn_mfma_f32_16x16x32_f16(a2[kb], b[j][kb], acc, 0, 0, 0);
      const float* wvp = wv[j >> 1];
      float v = 0.f;
      #pragma unroll
      for (int r = 0; r < 4; ++r) v += fmaxf(acc[r], 0.f) * wvp[r];
      vsum[j] += v;
    }
  }

  #pragma unroll
  for (int j = 0; j < 4; ++j) {
    float v = vsum[j];
    v += __shfl_xor(v, 16);
    v += __shfl_xor(v, 32);
    if (lane < 16) out[(size_t)g * GD + (wave * 4 + j) * 16 + lo] = v;
  }
}

extern "C" void kernel_launch(void* const* d_in, const int* in_sizes, int n_in,
                              void* d_out, int out_size, void* d_ws, size_t ws_size,
                              hipStream_t stream) {
  const float* E   = (const float*)d_in[0];
  const int*   map = (const int*)d_in[1];
  const float* w1s = (const float*)d_in[3];
  const float* w2s = (const float*)d_in[4];
  const float* w1t = (const float*)d_in[5];
  const float* w2t = (const float*)d_in[6];
  const int V = in_sizes[0] / VD;
  const int G = NGRAPH;

  char* ws = (char*)d_ws;
  size_t off = 0;
  float* scores = (float*)(ws + off); off += (size_t)V * NH * 4;
  int* gs = (int*)(ws + off); off += (size_t)(G + 1) * 4;
  off = (off + 255) & ~(size_t)255;
  f16* W1sp = (f16*)(ws + off); off += (size_t)VD * HID * 2;
  f16* W1tp = (f16*)(ws + off); off += (size_t)VD * HID * 2;
  f16* W2tp = (f16*)(ws + off); off += (size_t)HID * GD * 2;
  f16* W2sp = (f16*)(ws + off); off += (size_t)HID * 16 * 2;
  off = (off + 255) & ~(size_t)255;
  f16* ht = (f16*)(ws + off);
  const size_t need_fused = off + (size_t)V * HID * 2;
  const bool fused = ws_size >= need_fused;

  k_prep<<<65, 256, 0, stream>>>(w1s, w1t, w2t, w2s, map,
                                 W1sp, W1tp, W2tp, W2sp, gs, V, G);

  const int ntiles = (V + RT - 1) / RT;
  const int grid1 = (ntiles + 3) / 4;
  k_stage1<<<grid1, 512, 0, stream>>>(
      E, V, ntiles, W1sp, W2sp, W1tp, scores, fused ? ht : nullptr);

  if (fused) {
    k_graph<<<G, 256, 0, stream>>>(ht, scores, W2tp, gs, (float*)d_out, V);
  } else {
    k_stats<<<G, 64, 0, stream>>>(scores, gs);
    k_transform2<<<G, 256, 0, stream>>>(E, V, W1tp, W2tp, scores, gs,
                                        (float*)d_out);
  }
}

// Round 11
// 254.171 us; speedup vs baseline: 1.3414x; 1.0814x over previous
//
#include <hip/hip_runtime.h>
#include <hip/hip_fp16.h>

#define VD 256
#define HID 128
#define GD 256
#define NH 8
#define NGRAPH 4000   // num_graphs only available as device scalar; grid needs host value.
#define RT 64         // rows per k_stage1 tile
#define MAXROWS 512   // k_graph LDS score-staging cap (avg graph = 125 rows)

typedef _Float16 f16;
typedef f16 f16x4 __attribute__((ext_vector_type(4)));
typedef f16 f16x8 __attribute__((ext_vector_type(8)));
typedef float f32x4 __attribute__((ext_vector_type(4)));

__device__ __forceinline__ f16x8 load_a_frag(const float* p) {
  float4 p0 = *(const float4*)(p);
  float4 p1 = *(const float4*)(p + 4);
  f16x8 v;
  v[0] = (f16)p0.x; v[1] = (f16)p0.y; v[2] = (f16)p0.z; v[3] = (f16)p0.w;
  v[4] = (f16)p1.x; v[5] = (f16)p1.y; v[6] = (f16)p1.z; v[7] = (f16)p1.w;
  return v;
}

// Pack B operand [K][Nsrc] f32 -> MFMA B-fragment order f16.
// frag (kb,nb): lane l, elem i holds B[kb*32 + (l>>4)*8 + i][nb*16 + (l&15)]
__device__ __forceinline__ void pack_b_dev(const float* __restrict__ src,
                                           f16* __restrict__ dst,
                                           int K, int Nsrc, int Ndst, int t) {
  int NB = Ndst / 16, KB = K / 32;
  int total = KB * NB * 64;
  if (t >= total) return;
  int lane = t & 63;
  int frag = t >> 6;
  int nb = frag % NB, kb = frag / NB;
  int col = nb * 16 + (lane & 15);
  int krow = kb * 32 + (lane >> 4) * 8;
  f16x8 o;
  #pragma unroll
  for (int i = 0; i < 8; ++i) {
    float v = (col < Nsrc) ? src[(size_t)(krow + i) * Nsrc + col] : 0.0f;
    o[i] = (f16)v;
  }
  *(f16x8*)(dst + (size_t)t * 8) = o;
}

// One launch for all weight packing + segment bounds.
__global__ __launch_bounds__(256) void k_prep(
    const float* __restrict__ w1s, const float* __restrict__ w1t,
    const float* __restrict__ w2t, const float* __restrict__ w2s,
    const int* __restrict__ map,
    f16* __restrict__ W1sp, f16* __restrict__ W1tp,
    f16* __restrict__ W2tp, f16* __restrict__ W2sp,
    int* __restrict__ gs, int V, int G) {
  int b = blockIdx.x;
  int tid = threadIdx.x;
  if (b < 16) {
    pack_b_dev(w1s, W1sp, VD, HID, HID, b * 256 + tid);
  } else if (b < 32) {
    pack_b_dev(w1t, W1tp, VD, HID, HID, (b - 16) * 256 + tid);
  } else if (b < 48) {
    pack_b_dev(w2t, W2tp, HID, GD, GD, (b - 32) * 256 + tid);
  } else if (b == 48) {
    pack_b_dev(w2s, W2sp, HID, NH, 16, tid);
  } else {
    int g = (b - 49) * 256 + tid;
    if (g > G) return;
    int lo = 0, hi = V;
    while (lo < hi) {
      int mid = (lo + hi) >> 1;
      if (map[mid] < g) lo = mid + 1; else hi = mid;
    }
    gs[g] = lo;
  }
}

// Phase 1: one pass over E. Grid-stride over 64-row tiles (8 tiles/block):
// B-frags register-resident across tiles; next tile's E prefetched into
// registers while current tile runs MFMA.
// waves_per_eu pinned to (4,4): LDS caps at 2 blocks/CU anyway; a higher
// occupancy target makes the allocator choose 64 VGPR and spill Bs/Bt
// (R5: +350 MB scratch traffic, 2.5x dur).
__global__ __attribute__((amdgpu_flat_work_group_size(512, 512),
                          amdgpu_waves_per_eu(4, 4))) void k_stage1(
    const float* __restrict__ E, int V, int ntiles,
    const f16* __restrict__ W1sp, const f16* __restrict__ W2sp,
    const f16* __restrict__ W1tp,
    float* __restrict__ scores, f16* __restrict__ ht) {
  __shared__ __attribute__((aligned(16))) f16 lE[RT][VD + 8];
  __shared__ __attribute__((aligned(16))) f16 lH[RT][HID + 8];
  __shared__ __attribute__((aligned(16))) f16 lT[RT][HID + 8];
  const int tid = threadIdx.x;
  const int wave = tid >> 6;
  const int lane = tid & 63;
  const int hi = lane >> 4;
  const int lo = lane & 15;
  const int srow = tid >> 6;        // staging: 8 chunks/thread
  const int scol = (tid & 63) * 4;

  // B fragments: loaded once per block, register-resident for all tiles.
  f16x8 Bs[8], Bt[8];
  #pragma unroll
  for (int kb = 0; kb < 8; ++kb) {
    Bs[kb] = *(const f16x8*)(W1sp + ((size_t)(kb * 8 + wave) * 64 + lane) * 8);
    Bt[kb] = *(const f16x8*)(W1tp + ((size_t)(kb * 8 + wave) * 64 + lane) * 8);
  }

  int t = blockIdx.x;
  if (t >= ntiles) return;
  const int stride = gridDim.x;

  float4 pf[8];
  {
    const int r0 = t * RT;
    #pragma unroll
    for (int p = 0; p < 8; ++p) {
      int grow = r0 + p * 8 + srow;
      pf[p] = (grow < V) ? *(const float4*)(E + (size_t)grow * VD + scol)
                         : make_float4(0.f, 0.f, 0.f, 0.f);
    }
  }

  while (t < ntiles) {
    const int r0 = t * RT;
    // Write prefetched tile -> LDS (convert f32->f16 once).
    #pragma unroll
    for (int p = 0; p < 8; ++p) {
      f16x4 h;
      h[0] = (f16)pf[p].x; h[1] = (f16)pf[p].y;
      h[2] = (f16)pf[p].z; h[3] = (f16)pf[p].w;
      *(f16x4*)&lE[p * 8 + srow][scol] = h;
    }
    // Issue next tile's loads (consumed at next iteration's LDS write).
    const int tn = t + stride;
    if (tn < ntiles) {
      const int rn = tn * RT;
      #pragma unroll
      for (int p = 0; p < 8; ++p) {
        int grow = rn + p * 8 + srow;
        pf[p] = (grow < V) ? *(const float4*)(E + (size_t)grow * VD + scol)
                           : make_float4(0.f, 0.f, 0.f, 0.f);
      }
    }
    __syncthreads();   // lE ready; lH/lT free

    // Stage 1: h_s/h_t col-block `wave` for all 4 m-tiles.
    #pragma unroll
    for (int m = 0; m < 4; ++m) {
      f32x4 as = {0.f, 0.f, 0.f, 0.f};
      f32x4 at = {0.f, 0.f, 0.f, 0.f};
      #pragma unroll
      for (int kb = 0; kb < 8; ++kb) {
        f16x8 a = *(const f16x8*)&lE[m * 16 + lo][kb * 32 + hi * 8];
        as = __builtin_amdgcn_mfma_f32_16x16x32_f16(a, Bs[kb], as, 0, 0, 0);
        at = __builtin_amdgcn_mfma_f32_16x16x32_f16(a, Bt[kb], at, 0, 0, 0);
      }
      #pragma unroll
      for (int r = 0; r < 4; ++r) {
        lH[m * 16 + hi * 4 + r][wave * 16 + lo] = (f16)fmaxf(as[r], 0.f);
        if (ht != nullptr)
          lT[m * 16 + hi * 4 + r][wave * 16 + lo] = (f16)fmaxf(at[r], 0.f);
      }
    }
    __syncthreads();   // lH/lT ready; lE reads done

    // ht -> global FIRST (fire-and-forget stores overlap the scores MFMA).
    if (ht != nullptr) {
      #pragma unroll
      for (int p = 0; p < 2; ++p) {
        int c = p * 512 + tid;
        int row = c >> 4;
        int col = (c & 15) * 8;
        int grow = r0 + row;
        if (grow < V)
          *(f16x8*)(ht + (size_t)grow * HID + col) = *(const f16x8*)&lT[row][col];
      }
    }

    // Stage 2 (waves 0-3): scores = h_s @ W2s for m-block = wave.
    if (wave < 4) {
      f16x8 a2[4];
      #pragma unroll
      for (int kb = 0; kb < 4; ++kb)
        a2[kb] = *(const f16x8*)&lH[wave * 16 + lo][kb * 32 + hi * 8];
      f32x4 acc = {0.f, 0.f, 0.f, 0.f};
      #pragma unroll
      for (int kb = 0; kb < 4; ++kb) {
        f16x8 b = *(const f16x8*)(W2sp + ((size_t)kb * 64 + lane) * 8);
        acc = __builtin_amdgcn_mfma_f32_16x16x32_f16(a2[kb], b, acc, 0, 0, 0);
      }
      if (lo < NH) {
        #pragma unroll
        for (int r = 0; r < 4; ++r) {
          int row = r0 + wave * 16 + hi * 4 + r;
          if (row < V) scores[(size_t)row * NH + lo] = acc[r];
        }
      }
    }
    t = tn;
  }
}

// Phase 2 fused with softmax stats: per-graph WG (4 waves). Graph's scores
// staged to LDS once (<=MAXROWS rows), stats computed from LDS, then LDS is
// overwritten in place with final softmax weights; main loop reads weights
// from LDS. Wave w owns cols [w*64, w*64+64); W2t B-frags in registers.
// NOTE (R8-R10): prefetch/thread-count/occupancy variants all regressed —
// the (4,4) VGPR budget is exactly saturated; do not add in-flight state.
__global__ __attribute__((amdgpu_flat_work_group_size(256, 256),
                          amdgpu_waves_per_eu(4, 4))) void k_graph(
    const f16* __restrict__ ht, const float* __restrict__ scores,
    const f16* __restrict__ W2tp, const int* __restrict__ gs,
    float* __restrict__ out, int V) {
  __shared__ float red[4][NH];
  __shared__ float lW[MAXROWS * NH];   // 16 KB
  const int g = blockIdx.x;
  const int tid = threadIdx.x;
  const int wave = tid >> 6;
  const int lane = tid & 63;
  const int hi = lane >> 4;
  const int lo = lane & 15;
  const int s = gs[g], e = gs[g + 1];
  const int n = e - s;

  if (n <= 0) {
    out[(size_t)g * GD + tid] = 0.f;
    return;
  }

  f16x8 b[4][4];
  #pragma unroll
  for (int j = 0; j < 4; ++j)
    #pragma unroll
    for (int kb = 0; kb < 4; ++kb)
      b[j][kb] = *(const f16x8*)(
          W2tp + ((size_t)(kb * 16 + wave * 4 + j) * 64 + lane) * 8);

  const int h0 = wave * 2, h1 = wave * 2 + 1;
  float m0, m1, ri0, ri1;
  const bool use_lds = (n <= MAXROWS);

  if (use_lds) {
    // Stage scores -> LDS (coalesced float4; n*2 chunks).
    for (int c = tid; c < n * 2; c += 256)
      *(float4*)&lW[c * 4] = *(const float4*)(scores + (size_t)s * NH + c * 4);
    __syncthreads();

    // Per-head max from LDS.
    float mx[NH];
    #pragma unroll
    for (int h = 0; h < NH; ++h) mx[h] = -1e30f;
    for (int i = tid; i < n; i += 256) {
      #pragma unroll
      for (int h = 0; h < NH; ++h) mx[h] = fmaxf(mx[h], lW[i * NH + h]);
    }
    #pragma unroll
    for (int off = 32; off >= 1; off >>= 1)
      #pragma unroll
      for (int h = 0; h < NH; ++h) mx[h] = fmaxf(mx[h], __shfl_xor(mx[h], off));
    if (lane == 0) {
      #pragma unroll
      for (int h = 0; h < NH; ++h) red[wave][h] = mx[h];
    }
    __syncthreads();
    #pragma unroll
    for (int h = 0; h < NH; ++h)
      mx[h] = fmaxf(fmaxf(red[0][h], red[1][h]), fmaxf(red[2][h], red[3][h]));
    __syncthreads();

    // Per-head sum of exp from LDS.
    float sm[NH];
    #pragma unroll
    for (int h = 0; h < NH; ++h) sm[h] = 0.f;
    for (int i = tid; i < n; i += 256) {
      #pragma unroll
      for (int h = 0; h < NH; ++h) sm[h] += __expf(lW[i * NH + h] - mx[h]);
    }
    #pragma unroll
    for (int off = 32; off >= 1; off >>= 1)
      #pragma unroll
      for (int h = 0; h < NH; ++h) sm[h] += __shfl_xor(sm[h], off);
    if (lane == 0) {
      #pragma unroll
      for (int h = 0; h < NH; ++h) red[wave][h] = sm[h];
    }
    __syncthreads();

    float rinv[NH];
    #pragma unroll
    for (int h = 0; h < NH; ++h)
      rinv[h] = 1.f / (red[0][h] + red[1][h] + red[2][h] + red[3][h]);

    // Overwrite LDS scores with final weights.
    for (int i = tid; i < n; i += 256) {
      #pragma unroll
      for (int h = 0; h < NH; ++h)
        lW[i * NH + h] = __expf(lW[i * NH + h] - mx[h]) * rinv[h];
    }
    __syncthreads();
    m0 = mx[h0]; m1 = mx[h1]; ri0 = rinv[h0]; ri1 = rinv[h1];
  } else {
    // Fallback: stats straight from global (rare: n > MAXROWS).
    float mx[NH];
    #pragma unroll
    for (int h = 0; h < NH; ++h) mx[h] = -1e30f;
    for (int i = s + tid; i < e; i += 256) {
      float4 s0 = *(const float4*)(scores + (size_t)i * NH);
      float4 s1 = *(const float4*)(scores + (size_t)i * NH + 4);
      mx[0] = fmaxf(mx[0], s0.x); mx[1] = fmaxf(mx[1], s0.y);
      mx[2] = fmaxf(mx[2], s0.z); mx[3] = fmaxf(mx[3], s0.w);
      mx[4] = fmaxf(mx[4], s1.x); mx[5] = fmaxf(mx[5], s1.y);
      mx[6] = fmaxf(mx[6], s1.z); mx[7] = fmaxf(mx[7], s1.w);
    }
    #pragma unroll
    for (int off = 32; off >= 1; off >>= 1)
      #pragma unroll
      for (int h = 0; h < NH; ++h) mx[h] = fmaxf(mx[h], __shfl_xor(mx[h], off));
    if (lane == 0) {
      #pragma unroll
      for (int h = 0; h < NH; ++h) red[wave][h] = mx[h];
    }
    __syncthreads();
    #pragma unroll
    for (int h = 0; h < NH; ++h)
      mx[h] = fmaxf(fmaxf(red[0][h], red[1][h]), fmaxf(red[2][h], red[3][h]));
    __syncthreads();

    float sm[NH];
    #pragma unroll
    for (int h = 0; h < NH; ++h) sm[h] = 0.f;
    for (int i = s + tid; i < e; i += 256) {
      float4 s0 = *(const float4*)(scores + (size_t)i * NH);
      float4 s1 = *(const float4*)(scores + (size_t)i * NH + 4);
      sm[0] += __expf(s0.x - mx[0]); sm[1] += __expf(s0.y - mx[1]);
      sm[2] += __expf(s0.z - mx[2]); sm[3] += __expf(s0.w - mx[3]);
      sm[4] += __expf(s1.x - mx[4]); sm[5] += __expf(s1.y - mx[5]);
      sm[6] += __expf(s1.z - mx[6]); sm[7] += __expf(s1.w - mx[7]);
    }
    #pragma unroll
    for (int off = 32; off >= 1; off >>= 1)
      #pragma unroll
      for (int h = 0; h < NH; ++h) sm[h] += __shfl_xor(sm[h], off);
    if (lane == 0) {
      #pragma unroll
      for (int h = 0; h < NH; ++h) red[wave][h] = sm[h];
    }
    __syncthreads();
    m0 = mx[h0]; m1 = mx[h1];
    ri0 = 1.f / (red[0][h0] + red[1][h0] + red[2][h0] + red[3][h0]);
    ri1 = 1.f / (red[0][h1] + red[1][h1] + red[2][h1] + red[3][h1]);
  }

  float vsum[4] = {0.f, 0.f, 0.f, 0.f};

  for (int cb = s; cb < e; cb += 16) {
    f16x8 a[4];
    int arow = cb + lo;
    int ar = arow < V ? arow : V - 1;
    #pragma unroll
    for (int kb = 0; kb < 4; ++kb)
      a[kb] = *(const f16x8*)(ht + (size_t)ar * HID + kb * 32 + hi * 8);

    int wr = cb + hi * 4;
    float wv[2][4];
    if (use_lds) {
      #pragma unroll
      for (int r = 0; r < 4; ++r) {
        int row = wr + r;
        bool in = row < e;
        int rel = in ? (row - s) : 0;
        wv[0][r] = in ? lW[rel * NH + h0] : 0.f;
        wv[1][r] = in ? lW[rel * NH + h1] : 0.f;
      }
    } else {
      #pragma unroll
      for (int r = 0; r < 4; ++r) {
        int row = wr + r;
        bool in = row < e;
        float sc0 = in ? scores[(size_t)row * NH + h0] : 0.f;
        float sc1 = in ? scores[(size_t)row * NH + h1] : 0.f;
        wv[0][r] = in ? __expf(sc0 - m0) * ri0 : 0.f;
        wv[1][r] = in ? __expf(sc1 - m1) * ri1 : 0.f;
      }
    }
    #pragma unroll
    for (int j = 0; j < 4; ++j) {
      f32x4 acc = {0.f, 0.f, 0.f, 0.f};
      #pragma unroll
      for (int kb = 0; kb < 4; ++kb)
        acc = __builtin_amdgcn_mfma_f32_16x16x32_f16(a[kb], b[j][kb], acc, 0, 0, 0);
      const float* wvp = wv[j >> 1];
      float v = 0.f;
      #pragma unroll
      for (int r = 0; r < 4; ++r) v += fmaxf(acc[r], 0.f) * wvp[r];
      vsum[j] += v;
    }
  }

  #pragma unroll
  for (int j = 0; j < 4; ++j) {
    float v = vsum[j];
    v += __shfl_xor(v, 16);
    v += __shfl_xor(v, 32);
    if (lane < 16) out[(size_t)g * GD + (wave * 4 + j) * 16 + lo] = v;
  }
}

// ---- fallback path (ws too small for ht): old stats + recompute kernels ----
__global__ __launch_bounds__(64) void k_stats(
    float* __restrict__ scores, const int* __restrict__ gs) {
  int g = blockIdx.x;
  int lane = threadIdx.x;
  int s = gs[g], e = gs[g + 1];
  if (e <= s) return;
  float mx[NH];
  #pragma unroll
  for (int h = 0; h < NH; ++h) mx[h] = -1e30f;
  for (int i = s + lane; i < e; i += 64) {
    float4 s0 = *(const float4*)(scores + (size_t)i * NH);
    float4 s1 = *(const float4*)(scores + (size_t)i * NH + 4);
    mx[0] = fmaxf(mx[0], s0.x); mx[1] = fmaxf(mx[1], s0.y);
    mx[2] = fmaxf(mx[2], s0.z); mx[3] = fmaxf(mx[3], s0.w);
    mx[4] = fmaxf(mx[4], s1.x); mx[5] = fmaxf(mx[5], s1.y);
    mx[6] = fmaxf(mx[6], s1.z); mx[7] = fmaxf(mx[7], s1.w);
  }
  #pragma unroll
  for (int off = 32; off >= 1; off >>= 1)
    #pragma unroll
    for (int h = 0; h < NH; ++h) mx[h] = fmaxf(mx[h], __shfl_xor(mx[h], off));
  float sm[NH];
  #pragma unroll
  for (int h = 0; h < NH; ++h) sm[h] = 0.f;
  for (int i = s + lane; i < e; i += 64) {
    float4 s0 = *(const float4*)(scores + (size_t)i * NH);
    float4 s1 = *(const float4*)(scores + (size_t)i * NH + 4);
    sm[0] += __expf(s0.x - mx[0]); sm[1] += __expf(s0.y - mx[1]);
    sm[2] += __expf(s0.z - mx[2]); sm[3] += __expf(s0.w - mx[3]);
    sm[4] += __expf(s1.x - mx[4]); sm[5] += __expf(s1.y - mx[5]);
    sm[6] += __expf(s1.z - mx[6]); sm[7] += __expf(s1.w - mx[7]);
  }
  #pragma unroll
  for (int off = 32; off >= 1; off >>= 1)
    #pragma unroll
    for (int h = 0; h < NH; ++h) sm[h] += __shfl_xor(sm[h], off);
  float rinv[NH];
  #pragma unroll
  for (int h = 0; h < NH; ++h) rinv[h] = 1.f / sm[h];
  for (int i = s + lane; i < e; i += 64) {
    float4 s0 = *(const float4*)(scores + (size_t)i * NH);
    float4 s1 = *(const float4*)(scores + (size_t)i * NH + 4);
    s0.x = __expf(s0.x - mx[0]) * rinv[0]; s0.y = __expf(s0.y - mx[1]) * rinv[1];
    s0.z = __expf(s0.z - mx[2]) * rinv[2]; s0.w = __expf(s0.w - mx[3]) * rinv[3];
    s1.x = __expf(s1.x - mx[4]) * rinv[4]; s1.y = __expf(s1.y - mx[5]) * rinv[5];
    s1.z = __expf(s1.z - mx[6]) * rinv[6]; s1.w = __expf(s1.w - mx[7]) * rinv[7];
    *(float4*)(scores + (size_t)i * NH) = s0;
    *(float4*)(scores + (size_t)i * NH + 4) = s1;
  }
}

__global__ __launch_bounds__(256, 2) void k_transform2(
    const float* __restrict__ E, int V,
    const f16* __restrict__ W1tp, const f16* __restrict__ W2tp,
    const float* __restrict__ w, const int* __restrict__ gs,
    float* __restrict__ out) {
  __shared__ f16 hl[16][HID + 8];
  const int g = blockIdx.x;
  const int wave = threadIdx.x >> 6;
  const int lane = threadIdx.x & 63;
  const int hi = lane >> 4;
  const int lo = lane & 15;
  const int s = gs[g], e = gs[g + 1];

  f16x8 b[4][4];
  #pragma unroll
  for (int j = 0; j < 4; ++j)
    #pragma unroll
    for (int kb = 0; kb < 4; ++kb)
      b[j][kb] = *(const f16x8*)(
          W2tp + ((size_t)(kb * 16 + wave * 4 + j) * 64 + lane) * 8);

  float vsum[4] = {0.f, 0.f, 0.f, 0.f};

  for (int cb = s; cb < e; cb += 16) {
    int arow = cb + lo;
    int ar = arow < V ? arow : V - 1;
    f16x8 a[8];
    const float* ep = E + (size_t)ar * VD + hi * 8;
    #pragma unroll
    for (int kb = 0; kb < 8; ++kb) a[kb] = load_a_frag(ep + kb * 32);

    __syncthreads();
    #pragma unroll
    for (int nn = 0; nn < 2; ++nn) {
      int n = wave * 2 + nn;
      f32x4 acc = {0.f, 0.f, 0.f, 0.f};
      #pragma unroll
      for (int kb = 0; kb < 8; ++kb) {
        f16x8 bb = *(const f16x8*)(W1tp + ((size_t)(kb * 8 + n) * 64 + lane) * 8);
        acc = __builtin_amdgcn_mfma_f32_16x16x32_f16(a[kb], bb, acc, 0, 0, 0);
      }
      #pragma unroll
      for (int r = 0; r < 4; ++r)
        hl[hi * 4 + r][n * 16 + lo] = (f16)fmaxf(acc[r], 0.f);
    }
    __syncthreads();

    int wr = cb + hi * 4;
    float wv[2][4];
    #pragma unroll
    for (int hh = 0; hh < 2; ++hh) {
      int head = wave * 2 + hh;
      #pragma unroll
      for (int r = 0; r < 4; ++r) {
        int row = wr + r;
        wv[hh][r] = (row < e) ? w[(size_t)row * NH + head] : 0.f;
      }
    }
    f16x8 a2[4];
    #pragma unroll
    for (int kb = 0; kb < 4; ++kb)
      a2[kb] = *(const f16x8*)&hl[lo][kb * 32 + hi * 8];
    #pragma unroll
    for (int j = 0; j < 4; ++j) {
      f32x4 acc = {0.f, 0.f, 0.f, 0.f};
      #pragma unroll
      for (int kb = 0; kb < 4; ++kb)
        acc = __builtin_amdgcn_mfma_f32_16x16x32_f16(a2[kb], b[j][kb], acc, 0, 0, 0);
      const float* wvp = wv[j >> 1];
      float v = 0.f;
      #pragma unroll
      for (int r = 0; r < 4; ++r) v += fmaxf(acc[r], 0.f) * wvp[r];
      vsum[j] += v;
    }
  }

  #pragma unroll
  for (int j = 0; j < 4; ++j) {
    float v = vsum[j];
    v += __shfl_xor(v, 16);
    v += __shfl_xor(v, 32);
    if (lane < 16) out[(size_t)g * GD + (wave * 4 + j) * 16 + lo] = v;
  }
}

extern "C" void kernel_launch(void* const* d_in, const int* in_sizes, int n_in,
                              void* d_out, int out_size, void* d_ws, size_t ws_size,
                              hipStream_t stream) {
  const float* E   = (const float*)d_in[0];
  const int*   map = (const int*)d_in[1];
  const float* w1s = (const float*)d_in[3];
  const float* w2s = (const float*)d_in[4];
  const float* w1t = (const float*)d_in[5];
  const float* w2t = (const float*)d_in[6];
  const int V = in_sizes[0] / VD;
  const int G = NGRAPH;

  char* ws = (char*)d_ws;
  size_t off = 0;
  float* scores = (float*)(ws + off); off += (size_t)V * NH * 4;
  int* gs = (int*)(ws + off); off += (size_t)(G + 1) * 4;
  off = (off + 255) & ~(size_t)255;
  f16* W1sp = (f16*)(ws + off); off += (size_t)VD * HID * 2;
  f16* W1tp = (f16*)(ws + off); off += (size_t)VD * HID * 2;
  f16* W2tp = (f16*)(ws + off); off += (size_t)HID * GD * 2;
  f16* W2sp = (f16*)(ws + off); off += (size_t)HID * 16 * 2;
  off = (off + 255) & ~(size_t)255;
  f16* ht = (f16*)(ws + off);
  const size_t need_fused = off + (size_t)V * HID * 2;
  const bool fused = ws_size >= need_fused;

  k_prep<<<65, 256, 0, stream>>>(w1s, w1t, w2t, w2s, map,
                                 W1sp, W1tp, W2tp, W2sp, gs, V, G);

  const int ntiles = (V + RT - 1) / RT;
  const int grid1 = (ntiles + 7) / 8;   // 8 tiles/block (R11: B-frag amortization)
  k_stage1<<<grid1, 512, 0, stream>>>(
      E, V, ntiles, W1sp, W2sp, W1tp, scores, fused ? ht : nullptr);

  if (fused) {
    k_graph<<<G, 256, 0, stream>>>(ht, scores, W2tp, gs, (float*)d_out, V);
  } else {
    k_stats<<<G, 64, 0, stream>>>(scores, gs);
    k_transform2<<<G, 256, 0, stream>>>(E, V, W1tp, W2tp, scores, gs,
                                        (float*)d_out);
  }
}

// Round 12
// 247.204 us; speedup vs baseline: 1.3792x; 1.0282x over previous
//
#include <hip/hip_runtime.h>
#include <hip/hip_fp16.h>

#define VD 256
#define HID 128
#define GD 256
#define NH 8
#define NGRAPH 4000   // num_graphs only available as device scalar; grid needs host value.
#define RT 64         // rows per k_stage1 tile
#define MAXROWS 512   // k_graph LDS score-staging cap (avg graph = 125 rows)

typedef _Float16 f16;
typedef f16 f16x4 __attribute__((ext_vector_type(4)));
typedef f16 f16x8 __attribute__((ext_vector_type(8)));
typedef float f32x4 __attribute__((ext_vector_type(4)));

__device__ __forceinline__ f16x8 load_a_frag(const float* p) {
  float4 p0 = *(const float4*)(p);
  float4 p1 = *(const float4*)(p + 4);
  f16x8 v;
  v[0] = (f16)p0.x; v[1] = (f16)p0.y; v[2] = (f16)p0.z; v[3] = (f16)p0.w;
  v[4] = (f16)p1.x; v[5] = (f16)p1.y; v[6] = (f16)p1.z; v[7] = (f16)p1.w;
  return v;
}

// Pack B operand [K][Nsrc] f32 -> MFMA B-fragment order f16.
// frag (kb,nb): lane l, elem i holds B[kb*32 + (l>>4)*8 + i][nb*16 + (l&15)]
__device__ __forceinline__ void pack_b_dev(const float* __restrict__ src,
                                           f16* __restrict__ dst,
                                           int K, int Nsrc, int Ndst, int t) {
  int NB = Ndst / 16, KB = K / 32;
  int total = KB * NB * 64;
  if (t >= total) return;
  int lane = t & 63;
  int frag = t >> 6;
  int nb = frag % NB, kb = frag / NB;
  int col = nb * 16 + (lane & 15);
  int krow = kb * 32 + (lane >> 4) * 8;
  f16x8 o;
  #pragma unroll
  for (int i = 0; i < 8; ++i) {
    float v = (col < Nsrc) ? src[(size_t)(krow + i) * Nsrc + col] : 0.0f;
    o[i] = (f16)v;
  }
  *(f16x8*)(dst + (size_t)t * 8) = o;
}

// One launch for all weight packing + segment bounds.
__global__ __launch_bounds__(256) void k_prep(
    const float* __restrict__ w1s, const float* __restrict__ w1t,
    const float* __restrict__ w2t, const float* __restrict__ w2s,
    const int* __restrict__ map,
    f16* __restrict__ W1sp, f16* __restrict__ W1tp,
    f16* __restrict__ W2tp, f16* __restrict__ W2sp,
    int* __restrict__ gs, int V, int G) {
  int b = blockIdx.x;
  int tid = threadIdx.x;
  if (b < 16) {
    pack_b_dev(w1s, W1sp, VD, HID, HID, b * 256 + tid);
  } else if (b < 32) {
    pack_b_dev(w1t, W1tp, VD, HID, HID, (b - 16) * 256 + tid);
  } else if (b < 48) {
    pack_b_dev(w2t, W2tp, HID, GD, GD, (b - 32) * 256 + tid);
  } else if (b == 48) {
    pack_b_dev(w2s, W2sp, HID, NH, 16, tid);
  } else {
    int g = (b - 49) * 256 + tid;
    if (g > G) return;
    int lo = 0, hi = V;
    while (lo < hi) {
      int mid = (lo + hi) >> 1;
      if (map[mid] < g) lo = mid + 1; else hi = mid;
    }
    gs[g] = lo;
  }
}

// Phase 1: one pass over E. Grid-stride over 64-row tiles (16 tiles/block):
// B-frags register-resident across tiles; next tile's E prefetched into
// registers while current tile runs MFMA.
// waves_per_eu pinned to (4,4): LDS caps at 2 blocks/CU anyway; a higher
// occupancy target makes the allocator choose 64 VGPR and spill Bs/Bt
// (R5: +350 MB scratch traffic, 2.5x dur).
__global__ __attribute__((amdgpu_flat_work_group_size(512, 512),
                          amdgpu_waves_per_eu(4, 4))) void k_stage1(
    const float* __restrict__ E, int V, int ntiles,
    const f16* __restrict__ W1sp, const f16* __restrict__ W2sp,
    const f16* __restrict__ W1tp,
    float* __restrict__ scores, f16* __restrict__ ht) {
  __shared__ __attribute__((aligned(16))) f16 lE[RT][VD + 8];
  __shared__ __attribute__((aligned(16))) f16 lH[RT][HID + 8];
  __shared__ __attribute__((aligned(16))) f16 lT[RT][HID + 8];
  const int tid = threadIdx.x;
  const int wave = tid >> 6;
  const int lane = tid & 63;
  const int hi = lane >> 4;
  const int lo = lane & 15;
  const int srow = tid >> 6;        // staging: 8 chunks/thread
  const int scol = (tid & 63) * 4;

  // B fragments: loaded once per block, register-resident for all tiles.
  f16x8 Bs[8], Bt[8];
  #pragma unroll
  for (int kb = 0; kb < 8; ++kb) {
    Bs[kb] = *(const f16x8*)(W1sp + ((size_t)(kb * 8 + wave) * 64 + lane) * 8);
    Bt[kb] = *(const f16x8*)(W1tp + ((size_t)(kb * 8 + wave) * 64 + lane) * 8);
  }

  int t = blockIdx.x;
  if (t >= ntiles) return;
  const int stride = gridDim.x;

  float4 pf[8];
  {
    const int r0 = t * RT;
    #pragma unroll
    for (int p = 0; p < 8; ++p) {
      int grow = r0 + p * 8 + srow;
      pf[p] = (grow < V) ? *(const float4*)(E + (size_t)grow * VD + scol)
                         : make_float4(0.f, 0.f, 0.f, 0.f);
    }
  }

  while (t < ntiles) {
    const int r0 = t * RT;
    // Write prefetched tile -> LDS (convert f32->f16 once).
    #pragma unroll
    for (int p = 0; p < 8; ++p) {
      f16x4 h;
      h[0] = (f16)pf[p].x; h[1] = (f16)pf[p].y;
      h[2] = (f16)pf[p].z; h[3] = (f16)pf[p].w;
      *(f16x4*)&lE[p * 8 + srow][scol] = h;
    }
    // Issue next tile's loads (consumed at next iteration's LDS write).
    const int tn = t + stride;
    if (tn < ntiles) {
      const int rn = tn * RT;
      #pragma unroll
      for (int p = 0; p < 8; ++p) {
        int grow = rn + p * 8 + srow;
        pf[p] = (grow < V) ? *(const float4*)(E + (size_t)grow * VD + scol)
                           : make_float4(0.f, 0.f, 0.f, 0.f);
      }
    }
    __syncthreads();   // lE ready; lH/lT free

    // Stage 1: h_s/h_t col-block `wave` for all 4 m-tiles.
    #pragma unroll
    for (int m = 0; m < 4; ++m) {
      f32x4 as = {0.f, 0.f, 0.f, 0.f};
      f32x4 at = {0.f, 0.f, 0.f, 0.f};
      #pragma unroll
      for (int kb = 0; kb < 8; ++kb) {
        f16x8 a = *(const f16x8*)&lE[m * 16 + lo][kb * 32 + hi * 8];
        as = __builtin_amdgcn_mfma_f32_16x16x32_f16(a, Bs[kb], as, 0, 0, 0);
        at = __builtin_amdgcn_mfma_f32_16x16x32_f16(a, Bt[kb], at, 0, 0, 0);
      }
      #pragma unroll
      for (int r = 0; r < 4; ++r) {
        lH[m * 16 + hi * 4 + r][wave * 16 + lo] = (f16)fmaxf(as[r], 0.f);
        if (ht != nullptr)
          lT[m * 16 + hi * 4 + r][wave * 16 + lo] = (f16)fmaxf(at[r], 0.f);
      }
    }
    __syncthreads();   // lH/lT ready; lE reads done

    // ht -> global FIRST (fire-and-forget stores overlap the scores MFMA).
    if (ht != nullptr) {
      #pragma unroll
      for (int p = 0; p < 2; ++p) {
        int c = p * 512 + tid;
        int row = c >> 4;
        int col = (c & 15) * 8;
        int grow = r0 + row;
        if (grow < V)
          *(f16x8*)(ht + (size_t)grow * HID + col) = *(const f16x8*)&lT[row][col];
      }
    }

    // Stage 2 (waves 0-3): scores = h_s @ W2s for m-block = wave.
    if (wave < 4) {
      f16x8 a2[4];
      #pragma unroll
      for (int kb = 0; kb < 4; ++kb)
        a2[kb] = *(const f16x8*)&lH[wave * 16 + lo][kb * 32 + hi * 8];
      f32x4 acc = {0.f, 0.f, 0.f, 0.f};
      #pragma unroll
      for (int kb = 0; kb < 4; ++kb) {
        f16x8 b = *(const f16x8*)(W2sp + ((size_t)kb * 64 + lane) * 8);
        acc = __builtin_amdgcn_mfma_f32_16x16x32_f16(a2[kb], b, acc, 0, 0, 0);
      }
      if (lo < NH) {
        #pragma unroll
        for (int r = 0; r < 4; ++r) {
          int row = r0 + wave * 16 + hi * 4 + r;
          if (row < V) scores[(size_t)row * NH + lo] = acc[r];
        }
      }
    }
    t = tn;
  }
}

// Phase 2 fused with softmax stats: per-graph WG (4 waves). Graph's scores
// staged to LDS once (<=MAXROWS rows), stats computed from LDS, then LDS is
// overwritten in place with final softmax weights; main loop reads weights
// from LDS. Wave w owns cols [w*64, w*64+64); W2t B-frags in registers.
// NOTE (R8-R10): prefetch/thread-count/occupancy variants all regressed —
// the (4,4) VGPR budget is exactly saturated; do not add in-flight state.
__global__ __attribute__((amdgpu_flat_work_group_size(256, 256),
                          amdgpu_waves_per_eu(4, 4))) void k_graph(
    const f16* __restrict__ ht, const float* __restrict__ scores,
    const f16* __restrict__ W2tp, const int* __restrict__ gs,
    float* __restrict__ out, int V) {
  __shared__ float red[4][NH];
  __shared__ float lW[MAXROWS * NH];   // 16 KB
  const int g = blockIdx.x;
  const int tid = threadIdx.x;
  const int wave = tid >> 6;
  const int lane = tid & 63;
  const int hi = lane >> 4;
  const int lo = lane & 15;
  const int s = gs[g], e = gs[g + 1];
  const int n = e - s;

  if (n <= 0) {
    out[(size_t)g * GD + tid] = 0.f;
    return;
  }

  f16x8 b[4][4];
  #pragma unroll
  for (int j = 0; j < 4; ++j)
    #pragma unroll
    for (int kb = 0; kb < 4; ++kb)
      b[j][kb] = *(const f16x8*)(
          W2tp + ((size_t)(kb * 16 + wave * 4 + j) * 64 + lane) * 8);

  const int h0 = wave * 2, h1 = wave * 2 + 1;
  float m0, m1, ri0, ri1;
  const bool use_lds = (n <= MAXROWS);

  if (use_lds) {
    // Stage scores -> LDS (coalesced float4; n*2 chunks).
    for (int c = tid; c < n * 2; c += 256)
      *(float4*)&lW[c * 4] = *(const float4*)(scores + (size_t)s * NH + c * 4);
    __syncthreads();

    // Per-head max from LDS.
    float mx[NH];
    #pragma unroll
    for (int h = 0; h < NH; ++h) mx[h] = -1e30f;
    for (int i = tid; i < n; i += 256) {
      #pragma unroll
      for (int h = 0; h < NH; ++h) mx[h] = fmaxf(mx[h], lW[i * NH + h]);
    }
    #pragma unroll
    for (int off = 32; off >= 1; off >>= 1)
      #pragma unroll
      for (int h = 0; h < NH; ++h) mx[h] = fmaxf(mx[h], __shfl_xor(mx[h], off));
    if (lane == 0) {
      #pragma unroll
      for (int h = 0; h < NH; ++h) red[wave][h] = mx[h];
    }
    __syncthreads();
    #pragma unroll
    for (int h = 0; h < NH; ++h)
      mx[h] = fmaxf(fmaxf(red[0][h], red[1][h]), fmaxf(red[2][h], red[3][h]));
    __syncthreads();

    // Per-head sum of exp from LDS.
    float sm[NH];
    #pragma unroll
    for (int h = 0; h < NH; ++h) sm[h] = 0.f;
    for (int i = tid; i < n; i += 256) {
      #pragma unroll
      for (int h = 0; h < NH; ++h) sm[h] += __expf(lW[i * NH + h] - mx[h]);
    }
    #pragma unroll
    for (int off = 32; off >= 1; off >>= 1)
      #pragma unroll
      for (int h = 0; h < NH; ++h) sm[h] += __shfl_xor(sm[h], off);
    if (lane == 0) {
      #pragma unroll
      for (int h = 0; h < NH; ++h) red[wave][h] = sm[h];
    }
    __syncthreads();

    float rinv[NH];
    #pragma unroll
    for (int h = 0; h < NH; ++h)
      rinv[h] = 1.f / (red[0][h] + red[1][h] + red[2][h] + red[3][h]);

    // Overwrite LDS scores with final weights.
    for (int i = tid; i < n; i += 256) {
      #pragma unroll
      for (int h = 0; h < NH; ++h)
        lW[i * NH + h] = __expf(lW[i * NH + h] - mx[h]) * rinv[h];
    }
    __syncthreads();
    m0 = mx[h0]; m1 = mx[h1]; ri0 = rinv[h0]; ri1 = rinv[h1];
  } else {
    // Fallback: stats straight from global (rare: n > MAXROWS).
    float mx[NH];
    #pragma unroll
    for (int h = 0; h < NH; ++h) mx[h] = -1e30f;
    for (int i = s + tid; i < e; i += 256) {
      float4 s0 = *(const float4*)(scores + (size_t)i * NH);
      float4 s1 = *(const float4*)(scores + (size_t)i * NH + 4);
      mx[0] = fmaxf(mx[0], s0.x); mx[1] = fmaxf(mx[1], s0.y);
      mx[2] = fmaxf(mx[2], s0.z); mx[3] = fmaxf(mx[3], s0.w);
      mx[4] = fmaxf(mx[4], s1.x); mx[5] = fmaxf(mx[5], s1.y);
      mx[6] = fmaxf(mx[6], s1.z); mx[7] = fmaxf(mx[7], s1.w);
    }
    #pragma unroll
    for (int off = 32; off >= 1; off >>= 1)
      #pragma unroll
      for (int h = 0; h < NH; ++h) mx[h] = fmaxf(mx[h], __shfl_xor(mx[h], off));
    if (lane == 0) {
      #pragma unroll
      for (int h = 0; h < NH; ++h) red[wave][h] = mx[h];
    }
    __syncthreads();
    #pragma unroll
    for (int h = 0; h < NH; ++h)
      mx[h] = fmaxf(fmaxf(red[0][h], red[1][h]), fmaxf(red[2][h], red[3][h]));
    __syncthreads();

    float sm[NH];
    #pragma unroll
    for (int h = 0; h < NH; ++h) sm[h] = 0.f;
    for (int i = s + tid; i < e; i += 256) {
      float4 s0 = *(const float4*)(scores + (size_t)i * NH);
      float4 s1 = *(const float4*)(scores + (size_t)i * NH + 4);
      sm[0] += __expf(s0.x - mx[0]); sm[1] += __expf(s0.y - mx[1]);
      sm[2] += __expf(s0.z - mx[2]); sm[3] += __expf(s0.w - mx[3]);
      sm[4] += __expf(s1.x - mx[4]); sm[5] += __expf(s1.y - mx[5]);
      sm[6] += __expf(s1.z - mx[6]); sm[7] += __expf(s1.w - mx[7]);
    }
    #pragma unroll
    for (int off = 32; off >= 1; off >>= 1)
      #pragma unroll
      for (int h = 0; h < NH; ++h) sm[h] += __shfl_xor(sm[h], off);
    if (lane == 0) {
      #pragma unroll
      for (int h = 0; h < NH; ++h) red[wave][h] = sm[h];
    }
    __syncthreads();
    m0 = mx[h0]; m1 = mx[h1];
    ri0 = 1.f / (red[0][h0] + red[1][h0] + red[2][h0] + red[3][h0]);
    ri1 = 1.f / (red[0][h1] + red[1][h1] + red[2][h1] + red[3][h1]);
  }

  float vsum[4] = {0.f, 0.f, 0.f, 0.f};

  for (int cb = s; cb < e; cb += 16) {
    f16x8 a[4];
    int arow = cb + lo;
    int ar = arow < V ? arow : V - 1;
    #pragma unroll
    for (int kb = 0; kb < 4; ++kb)
      a[kb] = *(const f16x8*)(ht + (size_t)ar * HID + kb * 32 + hi * 8);

    int wr = cb + hi * 4;
    float wv[2][4];
    if (use_lds) {
      #pragma unroll
      for (int r = 0; r < 4; ++r) {
        int row = wr + r;
        bool in = row < e;
        int rel = in ? (row - s) : 0;
        wv[0][r] = in ? lW[rel * NH + h0] : 0.f;
        wv[1][r] = in ? lW[rel * NH + h1] : 0.f;
      }
    } else {
      #pragma unroll
      for (int r = 0; r < 4; ++r) {
        int row = wr + r;
        bool in = row < e;
        float sc0 = in ? scores[(size_t)row * NH + h0] : 0.f;
        float sc1 = in ? scores[(size_t)row * NH + h1] : 0.f;
        wv[0][r] = in ? __expf(sc0 - m0) * ri0 : 0.f;
        wv[1][r] = in ? __expf(sc1 - m1) * ri1 : 0.f;
      }
    }
    #pragma unroll
    for (int j = 0; j < 4; ++j) {
      f32x4 acc = {0.f, 0.f, 0.f, 0.f};
      #pragma unroll
      for (int kb = 0; kb < 4; ++kb)
        acc = __builtin_amdgcn_mfma_f32_16x16x32_f16(a[kb], b[j][kb], acc, 0, 0, 0);
      const float* wvp = wv[j >> 1];
      float v = 0.f;
      #pragma unroll
      for (int r = 0; r < 4; ++r) v += fmaxf(acc[r], 0.f) * wvp[r];
      vsum[j] += v;
    }
  }

  #pragma unroll
  for (int j = 0; j < 4; ++j) {
    float v = vsum[j];
    v += __shfl_xor(v, 16);
    v += __shfl_xor(v, 32);
    if (lane < 16) out[(size_t)g * GD + (wave * 4 + j) * 16 + lo] = v;
  }
}

// ---- fallback path (ws too small for ht): old stats + recompute kernels ----
__global__ __launch_bounds__(64) void k_stats(
    float* __restrict__ scores, const int* __restrict__ gs) {
  int g = blockIdx.x;
  int lane = threadIdx.x;
  int s = gs[g], e = gs[g + 1];
  if (e <= s) return;
  float mx[NH];
  #pragma unroll
  for (int h = 0; h < NH; ++h) mx[h] = -1e30f;
  for (int i = s + lane; i < e; i += 64) {
    float4 s0 = *(const float4*)(scores + (size_t)i * NH);
    float4 s1 = *(const float4*)(scores + (size_t)i * NH + 4);
    mx[0] = fmaxf(mx[0], s0.x); mx[1] = fmaxf(mx[1], s0.y);
    mx[2] = fmaxf(mx[2], s0.z); mx[3] = fmaxf(mx[3], s0.w);
    mx[4] = fmaxf(mx[4], s1.x); mx[5] = fmaxf(mx[5], s1.y);
    mx[6] = fmaxf(mx[6], s1.z); mx[7] = fmaxf(mx[7], s1.w);
  }
  #pragma unroll
  for (int off = 32; off >= 1; off >>= 1)
    #pragma unroll
    for (int h = 0; h < NH; ++h) mx[h] = fmaxf(mx[h], __shfl_xor(mx[h], off));
  float sm[NH];
  #pragma unroll
  for (int h = 0; h < NH; ++h) sm[h] = 0.f;
  for (int i = s + lane; i < e; i += 64) {
    float4 s0 = *(const float4*)(scores + (size_t)i * NH);
    float4 s1 = *(const float4*)(scores + (size_t)i * NH + 4);
    sm[0] += __expf(s0.x - mx[0]); sm[1] += __expf(s0.y - mx[1]);
    sm[2] += __expf(s0.z - mx[2]); sm[3] += __expf(s0.w - mx[3]);
    sm[4] += __expf(s1.x - mx[4]); sm[5] += __expf(s1.y - mx[5]);
    sm[6] += __expf(s1.z - mx[6]); sm[7] += __expf(s1.w - mx[7]);
  }
  #pragma unroll
  for (int off = 32; off >= 1; off >>= 1)
    #pragma unroll
    for (int h = 0; h < NH; ++h) sm[h] += __shfl_xor(sm[h], off);
  float rinv[NH];
  #pragma unroll
  for (int h = 0; h < NH; ++h) rinv[h] = 1.f / sm[h];
  for (int i = s + lane; i < e; i += 64) {
    float4 s0 = *(const float4*)(scores + (size_t)i * NH);
    float4 s1 = *(const float4*)(scores + (size_t)i * NH + 4);
    s0.x = __expf(s0.x - mx[0]) * rinv[0]; s0.y = __expf(s0.y - mx[1]) * rinv[1];
    s0.z = __expf(s0.z - mx[2]) * rinv[2]; s0.w = __expf(s0.w - mx[3]) * rinv[3];
    s1.x = __expf(s1.x - mx[4]) * rinv[4]; s1.y = __expf(s1.y - mx[5]) * rinv[5];
    s1.z = __expf(s1.z - mx[6]) * rinv[6]; s1.w = __expf(s1.w - mx[7]) * rinv[7];
    *(float4*)(scores + (size_t)i * NH) = s0;
    *(float4*)(scores + (size_t)i * NH + 4) = s1;
  }
}

__global__ __launch_bounds__(256, 2) void k_transform2(
    const float* __restrict__ E, int V,
    const f16* __restrict__ W1tp, const f16* __restrict__ W2tp,
    const float* __restrict__ w, const int* __restrict__ gs,
    float* __restrict__ out) {
  __shared__ f16 hl[16][HID + 8];
  const int g = blockIdx.x;
  const int wave = threadIdx.x >> 6;
  const int lane = threadIdx.x & 63;
  const int hi = lane >> 4;
  const int lo = lane & 15;
  const int s = gs[g], e = gs[g + 1];

  f16x8 b[4][4];
  #pragma unroll
  for (int j = 0; j < 4; ++j)
    #pragma unroll
    for (int kb = 0; kb < 4; ++kb)
      b[j][kb] = *(const f16x8*)(
          W2tp + ((size_t)(kb * 16 + wave * 4 + j) * 64 + lane) * 8);

  float vsum[4] = {0.f, 0.f, 0.f, 0.f};

  for (int cb = s; cb < e; cb += 16) {
    int arow = cb + lo;
    int ar = arow < V ? arow : V - 1;
    f16x8 a[8];
    const float* ep = E + (size_t)ar * VD + hi * 8;
    #pragma unroll
    for (int kb = 0; kb < 8; ++kb) a[kb] = load_a_frag(ep + kb * 32);

    __syncthreads();
    #pragma unroll
    for (int nn = 0; nn < 2; ++nn) {
      int n = wave * 2 + nn;
      f32x4 acc = {0.f, 0.f, 0.f, 0.f};
      #pragma unroll
      for (int kb = 0; kb < 8; ++kb) {
        f16x8 bb = *(const f16x8*)(W1tp + ((size_t)(kb * 8 + n) * 64 + lane) * 8);
        acc = __builtin_amdgcn_mfma_f32_16x16x32_f16(a[kb], bb, acc, 0, 0, 0);
      }
      #pragma unroll
      for (int r = 0; r < 4; ++r)
        hl[hi * 4 + r][n * 16 + lo] = (f16)fmaxf(acc[r], 0.f);
    }
    __syncthreads();

    int wr = cb + hi * 4;
    float wv[2][4];
    #pragma unroll
    for (int hh = 0; hh < 2; ++hh) {
      int head = wave * 2 + hh;
      #pragma unroll
      for (int r = 0; r < 4; ++r) {
        int row = wr + r;
        wv[hh][r] = (row < e) ? w[(size_t)row * NH + head] : 0.f;
      }
    }
    f16x8 a2[4];
    #pragma unroll
    for (int kb = 0; kb < 4; ++kb)
      a2[kb] = *(const f16x8*)&hl[lo][kb * 32 + hi * 8];
    #pragma unroll
    for (int j = 0; j < 4; ++j) {
      f32x4 acc = {0.f, 0.f, 0.f, 0.f};
      #pragma unroll
      for (int kb = 0; kb < 4; ++kb)
        acc = __builtin_amdgcn_mfma_f32_16x16x32_f16(a2[kb], b[j][kb], acc, 0, 0, 0);
      const float* wvp = wv[j >> 1];
      float v = 0.f;
      #pragma unroll
      for (int r = 0; r < 4; ++r) v += fmaxf(acc[r], 0.f) * wvp[r];
      vsum[j] += v;
    }
  }

  #pragma unroll
  for (int j = 0; j < 4; ++j) {
    float v = vsum[j];
    v += __shfl_xor(v, 16);
    v += __shfl_xor(v, 32);
    if (lane < 16) out[(size_t)g * GD + (wave * 4 + j) * 16 + lo] = v;
  }
}

extern "C" void kernel_launch(void* const* d_in, const int* in_sizes, int n_in,
                              void* d_out, int out_size, void* d_ws, size_t ws_size,
                              hipStream_t stream) {
  const float* E   = (const float*)d_in[0];
  const int*   map = (const int*)d_in[1];
  const float* w1s = (const float*)d_in[3];
  const float* w2s = (const float*)d_in[4];
  const float* w1t = (const float*)d_in[5];
  const float* w2t = (const float*)d_in[6];
  const int V = in_sizes[0] / VD;
  const int G = NGRAPH;

  char* ws = (char*)d_ws;
  size_t off = 0;
  float* scores = (float*)(ws + off); off += (size_t)V * NH * 4;
  int* gs = (int*)(ws + off); off += (size_t)(G + 1) * 4;
  off = (off + 255) & ~(size_t)255;
  f16* W1sp = (f16*)(ws + off); off += (size_t)VD * HID * 2;
  f16* W1tp = (f16*)(ws + off); off += (size_t)VD * HID * 2;
  f16* W2tp = (f16*)(ws + off); off += (size_t)HID * GD * 2;
  f16* W2sp = (f16*)(ws + off); off += (size_t)HID * 16 * 2;
  off = (off + 255) & ~(size_t)255;
  f16* ht = (f16*)(ws + off);
  const size_t need_fused = off + (size_t)V * HID * 2;
  const bool fused = ws_size >= need_fused;

  k_prep<<<65, 256, 0, stream>>>(w1s, w1t, w2t, w2s, map,
                                 W1sp, W1tp, W2tp, W2sp, gs, V, G);

  const int ntiles = (V + RT - 1) / RT;
  const int grid1 = (ntiles + 15) / 16;  // 16 tiles/block (R12: deeper B-frag
                                         // amortization; 489 blocks, 1 round)
  k_stage1<<<grid1, 512, 0, stream>>>(
      E, V, ntiles, W1sp, W2sp, W1tp, scores, fused ? ht : nullptr);

  if (fused) {
    k_graph<<<G, 256, 0, stream>>>(ht, scores, W2tp, gs, (float*)d_out, V);
  } else {
    k_stats<<<G, 64, 0, stream>>>(scores, gs);
    k_transform2<<<G, 256, 0, stream>>>(E, V, W1tp, W2tp, scores, gs,
                                        (float*)d_out);
  }
}

// Round 13
// 241.418 us; speedup vs baseline: 1.4123x; 1.0240x over previous
//
#include <hip/hip_runtime.h>
#include <hip/hip_fp16.h>

#define VD 256
#define HID 128
#define GD 256
#define NH 8
#define NGRAPH 4000   // num_graphs only available as device scalar; grid needs host value.
#define RT 64         // rows per k_stage1 tile
#define MAXROWS 512   // k_graph LDS score-staging cap (avg graph = 125 rows)

typedef _Float16 f16;
typedef f16 f16x4 __attribute__((ext_vector_type(4)));
typedef f16 f16x8 __attribute__((ext_vector_type(8)));
typedef float f32x4 __attribute__((ext_vector_type(4)));

__device__ __forceinline__ f16x8 load_a_frag(const float* p) {
  float4 p0 = *(const float4*)(p);
  float4 p1 = *(const float4*)(p + 4);
  f16x8 v;
  v[0] = (f16)p0.x; v[1] = (f16)p0.y; v[2] = (f16)p0.z; v[3] = (f16)p0.w;
  v[4] = (f16)p1.x; v[5] = (f16)p1.y; v[6] = (f16)p1.z; v[7] = (f16)p1.w;
  return v;
}

// Pack B operand [K][Nsrc] f32 -> MFMA B-fragment order f16.
// frag (kb,nb): lane l, elem i holds B[kb*32 + (l>>4)*8 + i][nb*16 + (l&15)]
__device__ __forceinline__ void pack_b_dev(const float* __restrict__ src,
                                           f16* __restrict__ dst,
                                           int K, int Nsrc, int Ndst, int t) {
  int NB = Ndst / 16, KB = K / 32;
  int total = KB * NB * 64;
  if (t >= total) return;
  int lane = t & 63;
  int frag = t >> 6;
  int nb = frag % NB, kb = frag / NB;
  int col = nb * 16 + (lane & 15);
  int krow = kb * 32 + (lane >> 4) * 8;
  f16x8 o;
  #pragma unroll
  for (int i = 0; i < 8; ++i) {
    float v = (col < Nsrc) ? src[(size_t)(krow + i) * Nsrc + col] : 0.0f;
    o[i] = (f16)v;
  }
  *(f16x8*)(dst + (size_t)t * 8) = o;
}

// One launch for all weight packing + segment bounds.
__global__ __launch_bounds__(256) void k_prep(
    const float* __restrict__ w1s, const float* __restrict__ w1t,
    const float* __restrict__ w2t, const float* __restrict__ w2s,
    const int* __restrict__ map,
    f16* __restrict__ W1sp, f16* __restrict__ W1tp,
    f16* __restrict__ W2tp, f16* __restrict__ W2sp,
    int* __restrict__ gs, int V, int G) {
  int b = blockIdx.x;
  int tid = threadIdx.x;
  if (b < 16) {
    pack_b_dev(w1s, W1sp, VD, HID, HID, b * 256 + tid);
  } else if (b < 32) {
    pack_b_dev(w1t, W1tp, VD, HID, HID, (b - 16) * 256 + tid);
  } else if (b < 48) {
    pack_b_dev(w2t, W2tp, HID, GD, GD, (b - 32) * 256 + tid);
  } else if (b == 48) {
    pack_b_dev(w2s, W2sp, HID, NH, 16, tid);
  } else {
    int g = (b - 49) * 256 + tid;
    if (g > G) return;
    int lo = 0, hi = V;
    while (lo < hi) {
      int mid = (lo + hi) >> 1;
      if (map[mid] < g) lo = mid + 1; else hi = mid;
    }
    gs[g] = lo;
  }
}

// Phase 1: one pass over E. Grid-stride over 64-row tiles (16 tiles/block):
// B-frags register-resident across tiles.
// R13: next-tile E loads are issued AFTER bar1 (not before). __syncthreads
// lowers to s_waitcnt vmcnt(0)+s_barrier [HIP-compiler], so loads issued
// before a barrier are fully drained there (zero overlap). Issuing after
// bar1 lets them fly under the whole stage-1 MFMA phase; only the
// remainder drains at bar2.
// waves_per_eu pinned to (4,4): LDS caps at 2 blocks/CU anyway; a higher
// occupancy target makes the allocator choose 64 VGPR and spill Bs/Bt
// (R5: +350 MB scratch traffic, 2.5x dur).
__global__ __attribute__((amdgpu_flat_work_group_size(512, 512),
                          amdgpu_waves_per_eu(4, 4))) void k_stage1(
    const float* __restrict__ E, int V, int ntiles,
    const f16* __restrict__ W1sp, const f16* __restrict__ W2sp,
    const f16* __restrict__ W1tp,
    float* __restrict__ scores, f16* __restrict__ ht) {
  __shared__ __attribute__((aligned(16))) f16 lE[RT][VD + 8];
  __shared__ __attribute__((aligned(16))) f16 lH[RT][HID + 8];
  __shared__ __attribute__((aligned(16))) f16 lT[RT][HID + 8];
  const int tid = threadIdx.x;
  const int wave = tid >> 6;
  const int lane = tid & 63;
  const int hi = lane >> 4;
  const int lo = lane & 15;
  const int srow = tid >> 6;        // staging: 8 chunks/thread
  const int scol = (tid & 63) * 4;

  // B fragments: loaded once per block, register-resident for all tiles.
  f16x8 Bs[8], Bt[8];
  #pragma unroll
  for (int kb = 0; kb < 8; ++kb) {
    Bs[kb] = *(const f16x8*)(W1sp + ((size_t)(kb * 8 + wave) * 64 + lane) * 8);
    Bt[kb] = *(const f16x8*)(W1tp + ((size_t)(kb * 8 + wave) * 64 + lane) * 8);
  }

  int t = blockIdx.x;
  if (t >= ntiles) return;
  const int stride = gridDim.x;

  float4 pf[8];
  {
    const int r0 = t * RT;
    #pragma unroll
    for (int p = 0; p < 8; ++p) {
      int grow = r0 + p * 8 + srow;
      pf[p] = (grow < V) ? *(const float4*)(E + (size_t)grow * VD + scol)
                         : make_float4(0.f, 0.f, 0.f, 0.f);
    }
  }

  while (t < ntiles) {
    const int r0 = t * RT;
    // Write prefetched tile -> LDS (convert f32->f16 once).
    #pragma unroll
    for (int p = 0; p < 8; ++p) {
      f16x4 h;
      h[0] = (f16)pf[p].x; h[1] = (f16)pf[p].y;
      h[2] = (f16)pf[p].z; h[3] = (f16)pf[p].w;
      *(f16x4*)&lE[p * 8 + srow][scol] = h;
    }
    __syncthreads();   // bar1: lE published; lH/lT free

    // Issue next tile's loads AFTER bar1 so they overlap the MFMA phase
    // below (issued-before-barrier loads would be drained by bar1's
    // vmcnt(0) with zero overlap).
    const int tn = t + stride;
    if (tn < ntiles) {
      const int rn = tn * RT;
      #pragma unroll
      for (int p = 0; p < 8; ++p) {
        int grow = rn + p * 8 + srow;
        pf[p] = (grow < V) ? *(const float4*)(E + (size_t)grow * VD + scol)
                           : make_float4(0.f, 0.f, 0.f, 0.f);
      }
    }

    // Stage 1: h_s/h_t col-block `wave` for all 4 m-tiles.
    #pragma unroll
    for (int m = 0; m < 4; ++m) {
      f32x4 as = {0.f, 0.f, 0.f, 0.f};
      f32x4 at = {0.f, 0.f, 0.f, 0.f};
      #pragma unroll
      for (int kb = 0; kb < 8; ++kb) {
        f16x8 a = *(const f16x8*)&lE[m * 16 + lo][kb * 32 + hi * 8];
        as = __builtin_amdgcn_mfma_f32_16x16x32_f16(a, Bs[kb], as, 0, 0, 0);
        at = __builtin_amdgcn_mfma_f32_16x16x32_f16(a, Bt[kb], at, 0, 0, 0);
      }
      #pragma unroll
      for (int r = 0; r < 4; ++r) {
        lH[m * 16 + hi * 4 + r][wave * 16 + lo] = (f16)fmaxf(as[r], 0.f);
        if (ht != nullptr)
          lT[m * 16 + hi * 4 + r][wave * 16 + lo] = (f16)fmaxf(at[r], 0.f);
      }
    }
    __syncthreads();   // bar2: lH/lT ready; drains the overlapped loads

    // ht -> global FIRST (fire-and-forget stores overlap the scores MFMA).
    if (ht != nullptr) {
      #pragma unroll
      for (int p = 0; p < 2; ++p) {
        int c = p * 512 + tid;
        int row = c >> 4;
        int col = (c & 15) * 8;
        int grow = r0 + row;
        if (grow < V)
          *(f16x8*)(ht + (size_t)grow * HID + col) = *(const f16x8*)&lT[row][col];
      }
    }

    // Stage 2 (waves 0-3): scores = h_s @ W2s for m-block = wave.
    if (wave < 4) {
      f16x8 a2[4];
      #pragma unroll
      for (int kb = 0; kb < 4; ++kb)
        a2[kb] = *(const f16x8*)&lH[wave * 16 + lo][kb * 32 + hi * 8];
      f32x4 acc = {0.f, 0.f, 0.f, 0.f};
      #pragma unroll
      for (int kb = 0; kb < 4; ++kb) {
        f16x8 b = *(const f16x8*)(W2sp + ((size_t)kb * 64 + lane) * 8);
        acc = __builtin_amdgcn_mfma_f32_16x16x32_f16(a2[kb], b, acc, 0, 0, 0);
      }
      if (lo < NH) {
        #pragma unroll
        for (int r = 0; r < 4; ++r) {
          int row = r0 + wave * 16 + hi * 4 + r;
          if (row < V) scores[(size_t)row * NH + lo] = acc[r];
        }
      }
    }
    t = tn;
  }
}

// Phase 2 fused with softmax stats: per-graph WG (4 waves). Graph's scores
// staged to LDS once (<=MAXROWS rows), stats computed from LDS, then LDS is
// overwritten in place with final softmax weights; main loop reads weights
// from LDS. Wave w owns cols [w*64, w*64+64); W2t B-frags in registers.
// NOTE (R8-R10): prefetch/thread-count/occupancy variants all regressed —
// the (4,4) VGPR budget is exactly saturated; do not add in-flight state.
__global__ __attribute__((amdgpu_flat_work_group_size(256, 256),
                          amdgpu_waves_per_eu(4, 4))) void k_graph(
    const f16* __restrict__ ht, const float* __restrict__ scores,
    const f16* __restrict__ W2tp, const int* __restrict__ gs,
    float* __restrict__ out, int V) {
  __shared__ float red[4][NH];
  __shared__ float lW[MAXROWS * NH];   // 16 KB
  const int g = blockIdx.x;
  const int tid = threadIdx.x;
  const int wave = tid >> 6;
  const int lane = tid & 63;
  const int hi = lane >> 4;
  const int lo = lane & 15;
  const int s = gs[g], e = gs[g + 1];
  const int n = e - s;

  if (n <= 0) {
    out[(size_t)g * GD + tid] = 0.f;
    return;
  }

  f16x8 b[4][4];
  #pragma unroll
  for (int j = 0; j < 4; ++j)
    #pragma unroll
    for (int kb = 0; kb < 4; ++kb)
      b[j][kb] = *(const f16x8*)(
          W2tp + ((size_t)(kb * 16 + wave * 4 + j) * 64 + lane) * 8);

  const int h0 = wave * 2, h1 = wave * 2 + 1;
  float m0, m1, ri0, ri1;
  const bool use_lds = (n <= MAXROWS);

  if (use_lds) {
    // Stage scores -> LDS (coalesced float4; n*2 chunks).
    for (int c = tid; c < n * 2; c += 256)
      *(float4*)&lW[c * 4] = *(const float4*)(scores + (size_t)s * NH + c * 4);
    __syncthreads();

    // Per-head max from LDS.
    float mx[NH];
    #pragma unroll
    for (int h = 0; h < NH; ++h) mx[h] = -1e30f;
    for (int i = tid; i < n; i += 256) {
      #pragma unroll
      for (int h = 0; h < NH; ++h) mx[h] = fmaxf(mx[h], lW[i * NH + h]);
    }
    #pragma unroll
    for (int off = 32; off >= 1; off >>= 1)
      #pragma unroll
      for (int h = 0; h < NH; ++h) mx[h] = fmaxf(mx[h], __shfl_xor(mx[h], off));
    if (lane == 0) {
      #pragma unroll
      for (int h = 0; h < NH; ++h) red[wave][h] = mx[h];
    }
    __syncthreads();
    #pragma unroll
    for (int h = 0; h < NH; ++h)
      mx[h] = fmaxf(fmaxf(red[0][h], red[1][h]), fmaxf(red[2][h], red[3][h]));
    __syncthreads();

    // Per-head sum of exp from LDS.
    float sm[NH];
    #pragma unroll
    for (int h = 0; h < NH; ++h) sm[h] = 0.f;
    for (int i = tid; i < n; i += 256) {
      #pragma unroll
      for (int h = 0; h < NH; ++h) sm[h] += __expf(lW[i * NH + h] - mx[h]);
    }
    #pragma unroll
    for (int off = 32; off >= 1; off >>= 1)
      #pragma unroll
      for (int h = 0; h < NH; ++h) sm[h] += __shfl_xor(sm[h], off);
    if (lane == 0) {
      #pragma unroll
      for (int h = 0; h < NH; ++h) red[wave][h] = sm[h];
    }
    __syncthreads();

    float rinv[NH];
    #pragma unroll
    for (int h = 0; h < NH; ++h)
      rinv[h] = 1.f / (red[0][h] + red[1][h] + red[2][h] + red[3][h]);

    // Overwrite LDS scores with final weights.
    for (int i = tid; i < n; i += 256) {
      #pragma unroll
      for (int h = 0; h < NH; ++h)
        lW[i * NH + h] = __expf(lW[i * NH + h] - mx[h]) * rinv[h];
    }
    __syncthreads();
    m0 = mx[h0]; m1 = mx[h1]; ri0 = rinv[h0]; ri1 = rinv[h1];
  } else {
    // Fallback: stats straight from global (rare: n > MAXROWS).
    float mx[NH];
    #pragma unroll
    for (int h = 0; h < NH; ++h) mx[h] = -1e30f;
    for (int i = s + tid; i < e; i += 256) {
      float4 s0 = *(const float4*)(scores + (size_t)i * NH);
      float4 s1 = *(const float4*)(scores + (size_t)i * NH + 4);
      mx[0] = fmaxf(mx[0], s0.x); mx[1] = fmaxf(mx[1], s0.y);
      mx[2] = fmaxf(mx[2], s0.z); mx[3] = fmaxf(mx[3], s0.w);
      mx[4] = fmaxf(mx[4], s1.x); mx[5] = fmaxf(mx[5], s1.y);
      mx[6] = fmaxf(mx[6], s1.z); mx[7] = fmaxf(mx[7], s1.w);
    }
    #pragma unroll
    for (int off = 32; off >= 1; off >>= 1)
      #pragma unroll
      for (int h = 0; h < NH; ++h) mx[h] = fmaxf(mx[h], __shfl_xor(mx[h], off));
    if (lane == 0) {
      #pragma unroll
      for (int h = 0; h < NH; ++h) red[wave][h] = mx[h];
    }
    __syncthreads();
    #pragma unroll
    for (int h = 0; h < NH; ++h)
      mx[h] = fmaxf(fmaxf(red[0][h], red[1][h]), fmaxf(red[2][h], red[3][h]));
    __syncthreads();

    float sm[NH];
    #pragma unroll
    for (int h = 0; h < NH; ++h) sm[h] = 0.f;
    for (int i = s + tid; i < e; i += 256) {
      float4 s0 = *(const float4*)(scores + (size_t)i * NH);
      float4 s1 = *(const float4*)(scores + (size_t)i * NH + 4);
      sm[0] += __expf(s0.x - mx[0]); sm[1] += __expf(s0.y - mx[1]);
      sm[2] += __expf(s0.z - mx[2]); sm[3] += __expf(s0.w - mx[3]);
      sm[4] += __expf(s1.x - mx[4]); sm[5] += __expf(s1.y - mx[5]);
      sm[6] += __expf(s1.z - mx[6]); sm[7] += __expf(s1.w - mx[7]);
    }
    #pragma unroll
    for (int off = 32; off >= 1; off >>= 1)
      #pragma unroll
      for (int h = 0; h < NH; ++h) sm[h] += __shfl_xor(sm[h], off);
    if (lane == 0) {
      #pragma unroll
      for (int h = 0; h < NH; ++h) red[wave][h] = sm[h];
    }
    __syncthreads();
    m0 = mx[h0]; m1 = mx[h1];
    ri0 = 1.f / (red[0][h0] + red[1][h0] + red[2][h0] + red[3][h0]);
    ri1 = 1.f / (red[0][h1] + red[1][h1] + red[2][h1] + red[3][h1]);
  }

  float vsum[4] = {0.f, 0.f, 0.f, 0.f};

  for (int cb = s; cb < e; cb += 16) {
    f16x8 a[4];
    int arow = cb + lo;
    int ar = arow < V ? arow : V - 1;
    #pragma unroll
    for (int kb = 0; kb < 4; ++kb)
      a[kb] = *(const f16x8*)(ht + (size_t)ar * HID + kb * 32 + hi * 8);

    int wr = cb + hi * 4;
    float wv[2][4];
    if (use_lds) {
      #pragma unroll
      for (int r = 0; r < 4; ++r) {
        int row = wr + r;
        bool in = row < e;
        int rel = in ? (row - s) : 0;
        wv[0][r] = in ? lW[rel * NH + h0] : 0.f;
        wv[1][r] = in ? lW[rel * NH + h1] : 0.f;
      }
    } else {
      #pragma unroll
      for (int r = 0; r < 4; ++r) {
        int row = wr + r;
        bool in = row < e;
        float sc0 = in ? scores[(size_t)row * NH + h0] : 0.f;
        float sc1 = in ? scores[(size_t)row * NH + h1] : 0.f;
        wv[0][r] = in ? __expf(sc0 - m0) * ri0 : 0.f;
        wv[1][r] = in ? __expf(sc1 - m1) * ri1 : 0.f;
      }
    }
    #pragma unroll
    for (int j = 0; j < 4; ++j) {
      f32x4 acc = {0.f, 0.f, 0.f, 0.f};
      #pragma unroll
      for (int kb = 0; kb < 4; ++kb)
        acc = __builtin_amdgcn_mfma_f32_16x16x32_f16(a[kb], b[j][kb], acc, 0, 0, 0);
      const float* wvp = wv[j >> 1];
      float v = 0.f;
      #pragma unroll
      for (int r = 0; r < 4; ++r) v += fmaxf(acc[r], 0.f) * wvp[r];
      vsum[j] += v;
    }
  }

  #pragma unroll
  for (int j = 0; j < 4; ++j) {
    float v = vsum[j];
    v += __shfl_xor(v, 16);
    v += __shfl_xor(v, 32);
    if (lane < 16) out[(size_t)g * GD + (wave * 4 + j) * 16 + lo] = v;
  }
}

// ---- fallback path (ws too small for ht): old stats + recompute kernels ----
__global__ __launch_bounds__(64) void k_stats(
    float* __restrict__ scores, const int* __restrict__ gs) {
  int g = blockIdx.x;
  int lane = threadIdx.x;
  int s = gs[g], e = gs[g + 1];
  if (e <= s) return;
  float mx[NH];
  #pragma unroll
  for (int h = 0; h < NH; ++h) mx[h] = -1e30f;
  for (int i = s + lane; i < e; i += 64) {
    float4 s0 = *(const float4*)(scores + (size_t)i * NH);
    float4 s1 = *(const float4*)(scores + (size_t)i * NH + 4);
    mx[0] = fmaxf(mx[0], s0.x); mx[1] = fmaxf(mx[1], s0.y);
    mx[2] = fmaxf(mx[2], s0.z); mx[3] = fmaxf(mx[3], s0.w);
    mx[4] = fmaxf(mx[4], s1.x); mx[5] = fmaxf(mx[5], s1.y);
    mx[6] = fmaxf(mx[6], s1.z); mx[7] = fmaxf(mx[7], s1.w);
  }
  #pragma unroll
  for (int off = 32; off >= 1; off >>= 1)
    #pragma unroll
    for (int h = 0; h < NH; ++h) mx[h] = fmaxf(mx[h], __shfl_xor(mx[h], off));
  float sm[NH];
  #pragma unroll
  for (int h = 0; h < NH; ++h) sm[h] = 0.f;
  for (int i = s + lane; i < e; i += 64) {
    float4 s0 = *(const float4*)(scores + (size_t)i * NH);
    float4 s1 = *(const float4*)(scores + (size_t)i * NH + 4);
    sm[0] += __expf(s0.x - mx[0]); sm[1] += __expf(s0.y - mx[1]);
    sm[2] += __expf(s0.z - mx[2]); sm[3] += __expf(s0.w - mx[3]);
    sm[4] += __expf(s1.x - mx[4]); sm[5] += __expf(s1.y - mx[5]);
    sm[6] += __expf(s1.z - mx[6]); sm[7] += __expf(s1.w - mx[7]);
  }
  #pragma unroll
  for (int off = 32; off >= 1; off >>= 1)
    #pragma unroll
    for (int h = 0; h < NH; ++h) sm[h] += __shfl_xor(sm[h], off);
  float rinv[NH];
  #pragma unroll
  for (int h = 0; h < NH; ++h) rinv[h] = 1.f / sm[h];
  for (int i = s + lane; i < e; i += 64) {
    float4 s0 = *(const float4*)(scores + (size_t)i * NH);
    float4 s1 = *(const float4*)(scores + (size_t)i * NH + 4);
    s0.x = __expf(s0.x - mx[0]) * rinv[0]; s0.y = __expf(s0.y - mx[1]) * rinv[1];
    s0.z = __expf(s0.z - mx[2]) * rinv[2]; s0.w = __expf(s0.w - mx[3]) * rinv[3];
    s1.x = __expf(s1.x - mx[4]) * rinv[4]; s1.y = __expf(s1.y - mx[5]) * rinv[5];
    s1.z = __expf(s1.z - mx[6]) * rinv[6]; s1.w = __expf(s1.w - mx[7]) * rinv[7];
    *(float4*)(scores + (size_t)i * NH) = s0;
    *(float4*)(scores + (size_t)i * NH + 4) = s1;
  }
}

__global__ __launch_bounds__(256, 2) void k_transform2(
    const float* __restrict__ E, int V,
    const f16* __restrict__ W1tp, const f16* __restrict__ W2tp,
    const float* __restrict__ w, const int* __restrict__ gs,
    float* __restrict__ out) {
  __shared__ f16 hl[16][HID + 8];
  const int g = blockIdx.x;
  const int wave = threadIdx.x >> 6;
  const int lane = threadIdx.x & 63;
  const int hi = lane >> 4;
  const int lo = lane & 15;
  const int s = gs[g], e = gs[g + 1];

  f16x8 b[4][4];
  #pragma unroll
  for (int j = 0; j < 4; ++j)
    #pragma unroll
    for (int kb = 0; kb < 4; ++kb)
      b[j][kb] = *(const f16x8*)(
          W2tp + ((size_t)(kb * 16 + wave * 4 + j) * 64 + lane) * 8);

  float vsum[4] = {0.f, 0.f, 0.f, 0.f};

  for (int cb = s; cb < e; cb += 16) {
    int arow = cb + lo;
    int ar = arow < V ? arow : V - 1;
    f16x8 a[8];
    const float* ep = E + (size_t)ar * VD + hi * 8;
    #pragma unroll
    for (int kb = 0; kb < 8; ++kb) a[kb] = load_a_frag(ep + kb * 32);

    __syncthreads();
    #pragma unroll
    for (int nn = 0; nn < 2; ++nn) {
      int n = wave * 2 + nn;
      f32x4 acc = {0.f, 0.f, 0.f, 0.f};
      #pragma unroll
      for (int kb = 0; kb < 8; ++kb) {
        f16x8 bb = *(const f16x8*)(W1tp + ((size_t)(kb * 8 + n) * 64 + lane) * 8);
        acc = __builtin_amdgcn_mfma_f32_16x16x32_f16(a[kb], bb, acc, 0, 0, 0);
      }
      #pragma unroll
      for (int r = 0; r < 4; ++r)
        hl[hi * 4 + r][n * 16 + lo] = (f16)fmaxf(acc[r], 0.f);
    }
    __syncthreads();

    int wr = cb + hi * 4;
    float wv[2][4];
    #pragma unroll
    for (int hh = 0; hh < 2; ++hh) {
      int head = wave * 2 + hh;
      #pragma unroll
      for (int r = 0; r < 4; ++r) {
        int row = wr + r;
        wv[hh][r] = (row < e) ? w[(size_t)row * NH + head] : 0.f;
      }
    }
    f16x8 a2[4];
    #pragma unroll
    for (int kb = 0; kb < 4; ++kb)
      a2[kb] = *(const f16x8*)&hl[lo][kb * 32 + hi * 8];
    #pragma unroll
    for (int j = 0; j < 4; ++j) {
      f32x4 acc = {0.f, 0.f, 0.f, 0.f};
      #pragma unroll
      for (int kb = 0; kb < 4; ++kb)
        acc = __builtin_amdgcn_mfma_f32_16x16x32_f16(a2[kb], b[j][kb], acc, 0, 0, 0);
      const float* wvp = wv[j >> 1];
      float v = 0.f;
      #pragma unroll
      for (int r = 0; r < 4; ++r) v += fmaxf(acc[r], 0.f) * wvp[r];
      vsum[j] += v;
    }
  }

  #pragma unroll
  for (int j = 0; j < 4; ++j) {
    float v = vsum[j];
    v += __shfl_xor(v, 16);
    v += __shfl_xor(v, 32);
    if (lane < 16) out[(size_t)g * GD + (wave * 4 + j) * 16 + lo] = v;
  }
}

extern "C" void kernel_launch(void* const* d_in, const int* in_sizes, int n_in,
                              void* d_out, int out_size, void* d_ws, size_t ws_size,
                              hipStream_t stream) {
  const float* E   = (const float*)d_in[0];
  const int*   map = (const int*)d_in[1];
  const float* w1s = (const float*)d_in[3];
  const float* w2s = (const float*)d_in[4];
  const float* w1t = (const float*)d_in[5];
  const float* w2t = (const float*)d_in[6];
  const int V = in_sizes[0] / VD;
  const int G = NGRAPH;

  char* ws = (char*)d_ws;
  size_t off = 0;
  float* scores = (float*)(ws + off); off += (size_t)V * NH * 4;
  int* gs = (int*)(ws + off); off += (size_t)(G + 1) * 4;
  off = (off + 255) & ~(size_t)255;
  f16* W1sp = (f16*)(ws + off); off += (size_t)VD * HID * 2;
  f16* W1tp = (f16*)(ws + off); off += (size_t)VD * HID * 2;
  f16* W2tp = (f16*)(ws + off); off += (size_t)HID * GD * 2;
  f16* W2sp = (f16*)(ws + off); off += (size_t)HID * 16 * 2;
  off = (off + 255) & ~(size_t)255;
  f16* ht = (f16*)(ws + off);
  const size_t need_fused = off + (size_t)V * HID * 2;
  const bool fused = ws_size >= need_fused;

  k_prep<<<65, 256, 0, stream>>>(w1s, w1t, w2t, w2s, map,
                                 W1sp, W1tp, W2tp, W2sp, gs, V, G);

  const int ntiles = (V + RT - 1) / RT;
  const int grid1 = (ntiles + 15) / 16;  // 16 tiles/block
  k_stage1<<<grid1, 512, 0, stream>>>(
      E, V, ntiles, W1sp, W2sp, W1tp, scores, fused ? ht : nullptr);

  if (fused) {
    k_graph<<<G, 256, 0, stream>>>(ht, scores, W2tp, gs, (float*)d_out, V);
  } else {
    k_stats<<<G, 64, 0, stream>>>(scores, gs);
    k_transform2<<<G, 256, 0, stream>>>(E, V, W1tp, W2tp, scores, gs,
                                        (float*)d_out);
  }
}